// Round 7
// baseline (292.793 us; speedup 1.0000x reference)
//
#include <hip/hip_runtime.h>
#include <hip/hip_bf16.h>

#define BB 2
#define SS 2048
#define INC 64
#define HIDN 512
#define NHH 8
#define HDD 64

typedef __attribute__((ext_vector_type(8))) short bf16x8;
typedef __attribute__((ext_vector_type(4))) float f32x4;

__device__ __forceinline__ short f2bf(float f) {
  union { __hip_bfloat16 h; short s; } u;
  u.h = __float2bfloat16(f);
  return u.s;
}
__device__ __forceinline__ float bf2f(short s) {
  return __uint_as_float(((unsigned)(unsigned short)s) << 16);
}

// ---------------------------------------------------------------------------
// conv + prep fused (independent work, one launch).
// blocks [0,512): conv  h[b,s,c] = relu(conv{1,2,3}(x)) -> bf16 hbf.
// blocks [512,768): prep — bf16 weight conversion + folded W2/cvec.
// ---------------------------------------------------------------------------
template <int KW, int OFF>
__device__ __forceinline__ void conv_channel(const float* __restrict__ w,
                                             const float* xs, float bias,
                                             float acc[8]) {
#pragma unroll
  for (int i = 0; i < 8; i++) acc[i] = bias;
#pragma unroll 4
  for (int ci = 0; ci < 64; ci++) {
    float xv[8 + KW - 1];
#pragma unroll
    for (int r = 0; r < 8 + KW - 1; r++) xv[r] = xs[(r + OFF) * 64 + ci];
#pragma unroll
    for (int k = 0; k < KW; k++) {
      float wv = w[ci * KW + k];
#pragma unroll
      for (int i = 0; i < 8; i++) acc[i] += xv[i + k] * wv;
    }
  }
}

__global__ __launch_bounds__(256) void conv_prep_kernel(
    const float* __restrict__ x, const float* __restrict__ w1,
    const float* __restrict__ b1, const float* __restrict__ w2,
    const float* __restrict__ b2, const float* __restrict__ w3,
    const float* __restrict__ b3, short* __restrict__ hbf,
    const float* __restrict__ Wq, const float* __restrict__ Wk_,
    const float* __restrict__ Wv_, const float* __restrict__ bq,
    const float* __restrict__ bk_, const float* __restrict__ bv_,
    const float* __restrict__ Wo, const float* __restrict__ Wkp,
    const float* __restrict__ Wvp, const float* __restrict__ bvp,
    short* __restrict__ Wallbf, float* __restrict__ ball,
    short* __restrict__ Wobf, short* __restrict__ Wkpbf,
    short* __restrict__ W2bf, float* __restrict__ cvec) {
  const int TS = 8;
  __shared__ float xs[(TS + 6) * 64];
  int tid = threadIdx.x;
  if (blockIdx.x < 512) {
    int blk = blockIdx.x;
    int b = blk / (SS / TS);
    int s0 = (blk % (SS / TS)) * TS;
    for (int i = tid; i < (TS + 6) * 64; i += 256) {
      int row = i >> 6, ci = i & 63;
      int sgl = s0 + row - 3;
      xs[i] = (sgl >= 0 && sgl < SS) ? x[(b * SS + sgl) * 64 + ci] : 0.f;
    }
    __syncthreads();
    for (int c = tid; c < 512; c += 256) {
      float acc[8];
      if (c < 171) {
        conv_channel<3, 2>(w1 + c * (64 * 3), xs, b1[c], acc);
      } else if (c < 342) {
        conv_channel<5, 1>(w2 + (c - 171) * (64 * 5), xs, b2[c - 171], acc);
      } else {
        conv_channel<7, 0>(w3 + (c - 342) * (64 * 7), xs, b3[c - 342], acc);
      }
#pragma unroll
      for (int i = 0; i < 8; i++) {
        float v = fmaxf(acc[i], 0.f);
        hbf[(b * SS + s0 + i) * 512 + c] = f2bf(v);
      }
    }
  } else {
    int i0 = (blockIdx.x - 512) * 256 + tid;
    int stride = 256 * 256;
    for (int idx = i0; idx < 786432; idx += stride) {
      float v;
      if (idx < 262144)      v = Wq[idx];
      else if (idx < 524288) v = Wk_[idx - 262144];
      else                   v = Wv_[idx - 524288];
      Wallbf[idx] = f2bf(v);
    }
    for (int idx = i0; idx < 262144; idx += stride) Wobf[idx] = f2bf(Wo[idx]);
    for (int idx = i0; idx < 4096; idx += stride) {
      Wkpbf[idx] = f2bf(Wkp[idx]);
      int j = idx >> 6, d = idx & 63;
      float s = 0.f;
#pragma unroll 8
      for (int i = 0; i < 64; i++) s += Wvp[j * 64 + i] * Wvp[i * 64 + d];
      W2bf[idx] = f2bf(s);
    }
    if (i0 < 1536) {
      float v;
      if (i0 < 512)       v = bq[i0];
      else if (i0 < 1024) v = bk_[i0 - 512];
      else                v = bv_[i0 - 1024];
      ball[i0] = v;
    }
    if (i0 < 64) {
      float s = bvp[i0];
#pragma unroll 8
      for (int i = 0; i < 64; i++) s += bvp[i] * Wvp[i0 * 64 + i];
      cvec[i0] = s;
    }
  }
}

// ---------------------------------------------------------------------------
// MFMA QKV gemm: 128-row blocks, wave = 32 rows x 64 cols, register
// double-buffer; unroll 2 so rotation removes the buffer copies.
// ---------------------------------------------------------------------------
__global__ __launch_bounds__(256, 4) void gemm_qkv(
    const short* __restrict__ Abf, const short* __restrict__ Wbf,
    const float* __restrict__ bias, short* __restrict__ Qh,
    short* __restrict__ Kh, short* __restrict__ Vh) {
  int m0 = blockIdx.x * 128;
  int n0 = blockIdx.y * 64;
  int tid = threadIdx.x;
  int wvv = tid >> 6, lane = tid & 63;
  int quad = lane >> 4, l16 = lane & 15;
  int mw = m0 + wvv * 32;
  const short* ap0 = Abf + (size_t)(mw + l16) * 512 + quad * 8;
  const short* ap1 = ap0 + 16 * 512;
  const short* bp = Wbf + (size_t)(n0 + l16) * 512 + quad * 8;
  f32x4 acc[2][4] = {};
  bf16x8 cA0 = *(const bf16x8*)ap0;
  bf16x8 cA1 = *(const bf16x8*)ap1;
  bf16x8 cB0 = *(const bf16x8*)(bp + 0 * 16 * 512);
  bf16x8 cB1 = *(const bf16x8*)(bp + 1 * 16 * 512);
  bf16x8 cB2 = *(const bf16x8*)(bp + 2 * 16 * 512);
  bf16x8 cB3 = *(const bf16x8*)(bp + 3 * 16 * 512);
#pragma unroll 2
  for (int ks = 0; ks < 16; ks++) {
    int offn = (ks + 1 < 16 ? ks + 1 : 15) * 32;
    bf16x8 nA0 = *(const bf16x8*)(ap0 + offn);
    bf16x8 nA1 = *(const bf16x8*)(ap1 + offn);
    bf16x8 nB0 = *(const bf16x8*)(bp + 0 * 16 * 512 + offn);
    bf16x8 nB1 = *(const bf16x8*)(bp + 1 * 16 * 512 + offn);
    bf16x8 nB2 = *(const bf16x8*)(bp + 2 * 16 * 512 + offn);
    bf16x8 nB3 = *(const bf16x8*)(bp + 3 * 16 * 512 + offn);
    acc[0][0] = __builtin_amdgcn_mfma_f32_16x16x32_bf16(cA0, cB0, acc[0][0], 0, 0, 0);
    acc[1][0] = __builtin_amdgcn_mfma_f32_16x16x32_bf16(cA1, cB0, acc[1][0], 0, 0, 0);
    acc[0][1] = __builtin_amdgcn_mfma_f32_16x16x32_bf16(cA0, cB1, acc[0][1], 0, 0, 0);
    acc[1][1] = __builtin_amdgcn_mfma_f32_16x16x32_bf16(cA1, cB1, acc[1][1], 0, 0, 0);
    acc[0][2] = __builtin_amdgcn_mfma_f32_16x16x32_bf16(cA0, cB2, acc[0][2], 0, 0, 0);
    acc[1][2] = __builtin_amdgcn_mfma_f32_16x16x32_bf16(cA1, cB2, acc[1][2], 0, 0, 0);
    acc[0][3] = __builtin_amdgcn_mfma_f32_16x16x32_bf16(cA0, cB3, acc[0][3], 0, 0, 0);
    acc[1][3] = __builtin_amdgcn_mfma_f32_16x16x32_bf16(cA1, cB3, acc[1][3], 0, 0, 0);
    cA0 = nA0; cA1 = nA1;
    cB0 = nB0; cB1 = nB1; cB2 = nB2; cB3 = nB3;
  }
  int which = n0 >> 9;
  int head = (n0 >> 6) & 7;
  short* dst = which == 0 ? Qh : (which == 1 ? Kh : Vh);
  float scale = which == 0 ? 0.125f : 1.0f;
#pragma unroll
  for (int mt = 0; mt < 2; mt++) {
#pragma unroll
    for (int r = 0; r < 4; r++) {
      int m = mw + mt * 16 + quad * 4 + r;
      int bb = m >> 11, s = m & 2047;
      size_t rowoff = ((size_t)(bb * 8 + head) * 2048 + s) * 64;
#pragma unroll
      for (int t = 0; t < 4; t++) {
        int hd = t * 16 + l16;
        float v = acc[mt][t][r] + bias[n0 + hd];
        dst[rowoff + hd] = f2bf(v * scale);
      }
    }
  }
}

// ---------------------------------------------------------------------------
// kpvp + local_attn fused (independent siblings of gemm_qkv, one launch).
// blocks [0,256): kpvp — Kph = K@Wkp.T+bkp (bf16); Vpp = V@W2+cvec (fp32).
// blocks [256,768): local windowed attention (one wave / 16-query tile).
// ---------------------------------------------------------------------------
__global__ __launch_bounds__(256, 4) void kpvp_local_kernel(
    const short* __restrict__ Kh, const short* __restrict__ Vh,
    const short* __restrict__ Wkpbf, const float* __restrict__ bkp,
    const short* __restrict__ W2bf, const float* __restrict__ cvec,
    short* __restrict__ Kph, float* __restrict__ Vpp,
    const short* __restrict__ Qh, float* __restrict__ ctxl) {
  int tid = threadIdx.x;
  __shared__ float Sloc[4][2][16][17];
  __shared__ float wloc[4][16][8];
  if (blockIdx.x < 256) {
    int m0 = blockIdx.x * 128;
    int wvv = tid >> 6, lane = tid & 63;
    int quad = lane >> 4, l16 = lane & 15;
    int mw = m0 + wvv * 32;
    {
      const short* ap0 = Kh + (size_t)(mw + l16) * 64 + quad * 8;
      const short* ap1 = ap0 + 16 * 64;
      const short* bp = Wkpbf + l16 * 64 + quad * 8;
      bf16x8 A00 = *(const bf16x8*)ap0, A01 = *(const bf16x8*)(ap0 + 32);
      bf16x8 A10 = *(const bf16x8*)ap1, A11 = *(const bf16x8*)(ap1 + 32);
      f32x4 acc[2][4] = {};
#pragma unroll
      for (int t = 0; t < 4; t++) {
        bf16x8 B0 = *(const bf16x8*)(bp + t * 16 * 64);
        bf16x8 B1 = *(const bf16x8*)(bp + t * 16 * 64 + 32);
        acc[0][t] = __builtin_amdgcn_mfma_f32_16x16x32_bf16(A00, B0, acc[0][t], 0, 0, 0);
        acc[0][t] = __builtin_amdgcn_mfma_f32_16x16x32_bf16(A01, B1, acc[0][t], 0, 0, 0);
        acc[1][t] = __builtin_amdgcn_mfma_f32_16x16x32_bf16(A10, B0, acc[1][t], 0, 0, 0);
        acc[1][t] = __builtin_amdgcn_mfma_f32_16x16x32_bf16(A11, B1, acc[1][t], 0, 0, 0);
      }
#pragma unroll
      for (int mt = 0; mt < 2; mt++)
#pragma unroll
        for (int r = 0; r < 4; r++) {
          int m = mw + mt * 16 + quad * 4 + r;
#pragma unroll
          for (int t = 0; t < 4; t++) {
            int n = t * 16 + l16;
            Kph[(size_t)m * 64 + n] = f2bf(acc[mt][t][r] + bkp[n]);
          }
        }
    }
    {
      const short* ap0 = Vh + (size_t)(mw + l16) * 64 + quad * 8;
      const short* ap1 = ap0 + 16 * 64;
      const short* bp = W2bf + l16 * 64 + quad * 8;
      bf16x8 A00 = *(const bf16x8*)ap0, A01 = *(const bf16x8*)(ap0 + 32);
      bf16x8 A10 = *(const bf16x8*)ap1, A11 = *(const bf16x8*)(ap1 + 32);
      f32x4 acc[2][4] = {};
#pragma unroll
      for (int t = 0; t < 4; t++) {
        bf16x8 B0 = *(const bf16x8*)(bp + t * 16 * 64);
        bf16x8 B1 = *(const bf16x8*)(bp + t * 16 * 64 + 32);
        acc[0][t] = __builtin_amdgcn_mfma_f32_16x16x32_bf16(A00, B0, acc[0][t], 0, 0, 0);
        acc[0][t] = __builtin_amdgcn_mfma_f32_16x16x32_bf16(A01, B1, acc[0][t], 0, 0, 0);
        acc[1][t] = __builtin_amdgcn_mfma_f32_16x16x32_bf16(A10, B0, acc[1][t], 0, 0, 0);
        acc[1][t] = __builtin_amdgcn_mfma_f32_16x16x32_bf16(A11, B1, acc[1][t], 0, 0, 0);
      }
#pragma unroll
      for (int mt = 0; mt < 2; mt++)
#pragma unroll
        for (int r = 0; r < 4; r++) {
          int m = mw + mt * 16 + quad * 4 + r;
#pragma unroll
          for (int t = 0; t < 4; t++) {
            int n = t * 16 + l16;
            Vpp[(size_t)m * 64 + n] = acc[mt][t][r] + cvec[n];
          }
        }
    }
    return;
  }
  // ---- local windowed attention ----
  int wv = tid >> 6;
  int tile = (blockIdx.x - 256) * 4 + wv;   // 0..2047
  int bh = tile >> 7;
  int q0 = (tile & 127) * 16;
  int lane = tid & 63;
  int quad = lane >> 4, l16 = lane & 15;

  const short* qbase = Qh + (size_t)(bh * 2048 + q0 + l16) * 64 + quad * 8;
  bf16x8 a0 = *(const bf16x8*)qbase;
  bf16x8 a1 = *(const bf16x8*)(qbase + 32);

  int k0a = min(max(q0 - 2 + l16, 0), 2047);
  int k1a = min(q0 + 6 + l16, 2047);
  const short* kb0 = Kh + (size_t)(bh * 2048 + k0a) * 64 + quad * 8;
  const short* kb1 = Kh + (size_t)(bh * 2048 + k1a) * 64 + quad * 8;
  bf16x8 B00 = *(const bf16x8*)kb0;
  bf16x8 B01 = *(const bf16x8*)(kb0 + 32);
  bf16x8 B10 = *(const bf16x8*)kb1;
  bf16x8 B11 = *(const bf16x8*)(kb1 + 32);
  f32x4 C0 = {0.f, 0.f, 0.f, 0.f};
  f32x4 C1 = {0.f, 0.f, 0.f, 0.f};
  C0 = __builtin_amdgcn_mfma_f32_16x16x32_bf16(a0, B00, C0, 0, 0, 0);
  C0 = __builtin_amdgcn_mfma_f32_16x16x32_bf16(a1, B01, C0, 0, 0, 0);
  C1 = __builtin_amdgcn_mfma_f32_16x16x32_bf16(a0, B10, C1, 0, 0, 0);
  C1 = __builtin_amdgcn_mfma_f32_16x16x32_bf16(a1, B11, C1, 0, 0, 0);
#pragma unroll
  for (int r = 0; r < 4; r++) {
    Sloc[wv][0][quad * 4 + r][l16] = C0[r];
    Sloc[wv][1][quad * 4 + r][l16] = C1[r];
  }
  __builtin_amdgcn_wave_barrier();
  if (lane < 16) {
    int q = lane;
    float sc[5];
    bool ok[5];
#pragma unroll
    for (int j = 0; j < 5; j++) {
      int offq = q + j - 2;
      int sg = q0 + offq;
      ok[j] = (sg >= 0 && sg < SS);
      int t = offq <= 13 ? 0 : 1;
      int col = t ? offq - 6 : offq + 2;
      sc[j] = ok[j] ? Sloc[wv][t][q][col] : -3.0e38f;
    }
    float m = -3.0e38f;
#pragma unroll
    for (int j = 0; j < 5; j++) m = fmaxf(m, sc[j]);
    float e[5], l = 0.f;
#pragma unroll
    for (int j = 0; j < 5; j++) {
      e[j] = ok[j] ? __expf(sc[j] - m) : 0.f;
      l += e[j];
    }
    float inv = 1.f / l;
#pragma unroll
    for (int j = 0; j < 5; j++) wloc[wv][q][j] = e[j] * inv;
  }
  __builtin_amdgcn_wave_barrier();
  {
    int q = lane >> 2, jb = (lane & 3) * 16;
    int s = q0 + q;
    float acc[16] = {};
#pragma unroll
    for (int j = 0; j < 5; j++) {
      int sg = s + j - 2;
      if (sg >= 0 && sg < SS) {
        float w = wloc[wv][q][j];
        const short* vr = Vh + (size_t)(bh * 2048 + sg) * 64 + jb;
#pragma unroll
        for (int u = 0; u < 16; u += 4) {
          short4 v4 = *(const short4*)(vr + u);
          acc[u + 0] += w * bf2f(v4.x);
          acc[u + 1] += w * bf2f(v4.y);
          acc[u + 2] += w * bf2f(v4.z);
          acc[u + 3] += w * bf2f(v4.w);
        }
      }
    }
    float* orow = ctxl + (size_t)(bh * 2048 + s) * 64 + jb;
#pragma unroll
    for (int u = 0; u < 16; u += 4)
      *(float4*)(orow + u) =
          make_float4(acc[u], acc[u + 1], acc[u + 2], acc[u + 3]);
  }
}

// ---------------------------------------------------------------------------
// global sparse attention — 2 waves per 16-query tile (key halves split).
// v7: XCD-AFFINITY BLOCK SWIZZLE (single change vs v6). All 64 block-pairs
// of one bh now share blockIdx%8, so each XCD's private L2 serves only 2 bh
// (Kph+Q ~1MB, Vpp+ctxl ~4MB) instead of all 16 (~40MB thrash). Rounds 1-6
// eliminated VALU throughput / occupancy / prefetch / reg-class as the
// 82us limiter; per-iteration stall arithmetic (~1000cy) matches deep-L2/
// HBM miss latency -> locality is the last untested axis.
// Mapping (bijective over 1024 blocks): bh = (p&7)*2 + (p>>9),
// pair-in-bh i = (p>>3)&63.
// ---------------------------------------------------------------------------
__global__ __launch_bounds__(256, 4) void global_attn(
    const short* __restrict__ Qh, const short* __restrict__ Kph,
    const float* __restrict__ Vpp, const float* __restrict__ ctxl,
    short* __restrict__ ctxcb) {
  int tid = threadIdx.x;
  int wv = tid >> 6;
  int lane = tid & 63;
  int quad = lane >> 4, l16 = lane & 15;
  int tb = wv >> 1;                    // tile within block-pair: 0,1
  int half = wv & 1;                   // key half: 0 -> keys 0..1023
  int p = blockIdx.x;
  int bh = (p & 7) * 2 + (p >> 9);     // XCD-affine head-batch index
  int tloc = ((p >> 3) & 63) * 2 + tb; // tile index within bh: 0..127
  int q0 = tloc * 16;

  __shared__ unsigned swl[4][16][17];  // per wave: sorted top-16 per query
  __shared__ float twl[2][16][17];
  __shared__ int   txl[2][16][17];

  const short* qbase = Qh + (size_t)(bh * 2048 + q0 + l16) * 64 + quad * 8;
  bf16x8 a0 = *(const bf16x8*)qbase;
  bf16x8 a1 = *(const bf16x8*)(qbase + 32);

  const short* kbase =
      Kph + (size_t)(bh * 2048 + half * 1024 + l16) * 64 + quad * 8;

  unsigned er[4][8];
#pragma unroll
  for (int a = 0; a < 4; a++)
#pragma unroll
    for (int j = 0; j < 8; j++) er[a][j] = 0u;

  // med3 sorted-insert: all outputs from OLD e + cand; depth-1, 8 ops.
  auto insert8 = [&](unsigned (&e)[8], unsigned cand) {
    unsigned n0, n1, n2, n3, n4, n5, n6, n7;
    asm("v_max_u32 %0, %1, %2" : "=v"(n0) : "v"(e[0]), "v"(cand));
    asm("v_med3_u32 %0, %1, %2, %3" : "=v"(n1) : "v"(e[0]), "v"(e[1]), "v"(cand));
    asm("v_med3_u32 %0, %1, %2, %3" : "=v"(n2) : "v"(e[1]), "v"(e[2]), "v"(cand));
    asm("v_med3_u32 %0, %1, %2, %3" : "=v"(n3) : "v"(e[2]), "v"(e[3]), "v"(cand));
    asm("v_med3_u32 %0, %1, %2, %3" : "=v"(n4) : "v"(e[3]), "v"(e[4]), "v"(cand));
    asm("v_med3_u32 %0, %1, %2, %3" : "=v"(n5) : "v"(e[4]), "v"(e[5]), "v"(cand));
    asm("v_med3_u32 %0, %1, %2, %3" : "=v"(n6) : "v"(e[5]), "v"(e[6]), "v"(cand));
    asm("v_med3_u32 %0, %1, %2, %3" : "=v"(n7) : "v"(e[6]), "v"(e[7]), "v"(cand));
    e[0] = n0; e[1] = n1; e[2] = n2; e[3] = n3;
    e[4] = n4; e[5] = n5; e[6] = n6; e[7] = n7;
  };
  auto mkcand = [&](float s, int idxr) -> unsigned {
    unsigned u = __float_as_uint(s);
    u ^= ((unsigned)((int)u >> 31)) | 0x80000000u;
    return (u & 0xFFFFF800u) | (unsigned)idxr;
  };

  int idxbase = 2047 - half * 1024 - l16;
#pragma unroll 1
  for (int g = 0; g < 64; g += 2) {
    bf16x8 B00 = *(const bf16x8*)(kbase + g * 1024);
    bf16x8 B01 = *(const bf16x8*)(kbase + g * 1024 + 32);
    bf16x8 B10 = *(const bf16x8*)(kbase + (g + 1) * 1024);
    bf16x8 B11 = *(const bf16x8*)(kbase + (g + 1) * 1024 + 32);
    f32x4 C0 = {0.f, 0.f, 0.f, 0.f};
    f32x4 C1 = {0.f, 0.f, 0.f, 0.f};
    C0 = __builtin_amdgcn_mfma_f32_16x16x32_bf16(a0, B00, C0, 0, 0, 0);
    C0 = __builtin_amdgcn_mfma_f32_16x16x32_bf16(a1, B01, C0, 0, 0, 0);
    C1 = __builtin_amdgcn_mfma_f32_16x16x32_bf16(a0, B10, C1, 0, 0, 0);
    C1 = __builtin_amdgcn_mfma_f32_16x16x32_bf16(a1, B11, C1, 0, 0, 0);
    int idxr0 = idxbase - (g << 4);
    int idxr1 = idxr0 - 16;
    insert8(er[0], mkcand(C0[0], idxr0));
    insert8(er[1], mkcand(C0[1], idxr0));
    insert8(er[2], mkcand(C0[2], idxr0));
    insert8(er[3], mkcand(C0[3], idxr0));
    insert8(er[0], mkcand(C1[0], idxr1));
    insert8(er[1], mkcand(C1[1], idxr1));
    insert8(er[2], mkcand(C1[2], idxr1));
    insert8(er[3], mkcand(C1[3], idxr1));
  }

  // Extraction: per wave, pop the top-16 of its half for each query (4
  // chains interleaved for ILP) and write sorted lists to LDS.
  {
    unsigned sw[4] = {0u, 0u, 0u, 0u};
#pragma unroll
    for (int t = 0; t < 16; t++) {
#pragma unroll
      for (int a = 0; a < 4; a++) {
        unsigned w = er[a][0];
#pragma unroll
        for (int mm = 1; mm <= 8; mm <<= 1) {
          unsigned o = (unsigned)__shfl_xor((int)w, mm);
          w = w > o ? w : o;
        }
        bool pop = (er[a][0] == w);
#pragma unroll
        for (int j = 0; j < 7; j++) er[a][j] = pop ? er[a][j + 1] : er[a][j];
        er[a][7] = pop ? 0u : er[a][7];
        if (l16 == t) sw[a] = w;
      }
    }
#pragma unroll
    for (int a = 0; a < 4; a++) swl[wv][quad * 4 + a][l16] = sw[a];
  }
  __syncthreads();

  // Merge the two halves' sorted-16 lists per query + softmax weights.
  if (tid < 32) {
    int tb2 = tid >> 4, q = tid & 15;
    const unsigned* A = swl[tb2 * 2][q];
    const unsigned* Bv = swl[tb2 * 2 + 1][q];
    auto decode = [&](unsigned w) -> float {
      unsigned wb = w & 0xFFFFF800u;
      unsigned uu = (w & 0x80000000u) ? (wb ^ 0x80000000u) : ~wb;
      return (w == 0u) ? -1.0e30f : __uint_as_float(uu);
    };
    unsigned h0 = A[0], h1 = Bv[0];
    float mval = decode(h0 > h1 ? h0 : h1);
    float lsum = 0.f;
    float ev[16];
    int ki[16];
#pragma unroll
    for (int i = 0; i < 16; i++) {
      unsigned wa = A[i], wb2 = Bv[15 - i];
      unsigned w = wa > wb2 ? wa : wb2;
      float sv = decode(w);
      float ex = __expf(sv - mval);
      lsum += ex;
      ev[i] = ex;
      ki[i] = 2047 - (int)(w & 0x7FFu);
    }
    float inv = 1.f / lsum;
#pragma unroll
    for (int i = 0; i < 16; i++) {
      twl[tb2][q][i] = ev[i] * inv;
      txl[tb2][q][i] = ki[i];
    }
  }
  __syncthreads();

  // Block-wide weighted gather of prefolded Vpp rows; combine with local ctx.
  {
    int tb2 = tid >> 7;
    int r = tid & 127;
    int q = r >> 3, d0 = (r & 7) * 8;
    int bh2 = (p & 7) * 2 + (p >> 9);
    int tloc2 = ((p >> 3) & 63) * 2 + tb2;
    int q02 = tloc2 * 16;
    int b = bh2 >> 3, hh = bh2 & 7;
    const float* vball = Vpp + (size_t)bh2 * (2048 * 64) + d0;
    float acc[8];
#pragma unroll
    for (int u = 0; u < 8; u++) acc[u] = 0.f;
#pragma unroll 4
    for (int j = 0; j < 16; j++) {
      float w = twl[tb2][q][j];
      const float* vr = vball + (size_t)txl[tb2][q][j] * 64;
      float4 v0 = *(const float4*)vr;
      float4 v1 = *(const float4*)(vr + 4);
      acc[0] += w * v0.x; acc[1] += w * v0.y;
      acc[2] += w * v0.z; acc[3] += w * v0.w;
      acc[4] += w * v1.x; acc[5] += w * v1.y;
      acc[6] += w * v1.z; acc[7] += w * v1.w;
    }
    int s = q02 + q;
    const float* lrow = ctxl + (size_t)(bh2 * 2048 + s) * 64 + d0;
    short* orow = ctxcb + (size_t)(b * 2048 + s) * 512 + hh * 64 + d0;
    float4 lv0 = *(const float4*)lrow;
    float4 lv1 = *(const float4*)(lrow + 4);
    short4 o0, o1;
    o0.x = f2bf(0.5f * (lv0.x + acc[0]));
    o0.y = f2bf(0.5f * (lv0.y + acc[1]));
    o0.z = f2bf(0.5f * (lv0.z + acc[2]));
    o0.w = f2bf(0.5f * (lv0.w + acc[3]));
    o1.x = f2bf(0.5f * (lv1.x + acc[4]));
    o1.y = f2bf(0.5f * (lv1.y + acc[5]));
    o1.z = f2bf(0.5f * (lv1.z + acc[6]));
    o1.w = f2bf(0.5f * (lv1.w + acc[7]));
    *(short4*)orow = o0;
    *(short4*)(orow + 4) = o1;
  }
}

// ---------------------------------------------------------------------------
// MFMA Wo gemm: 128-row blocks, wave = 32 rows; unroll 2 removes copies.
// Residual from bf16 hbf.
// ---------------------------------------------------------------------------
__global__ __launch_bounds__(256, 4) void gemm_wo(
    const short* __restrict__ Abf, const short* __restrict__ Wbf,
    const float* __restrict__ bo, const short* __restrict__ hbf,
    float* __restrict__ outp) {
  int m0 = blockIdx.x * 128;
  int n0 = blockIdx.y * 64;
  int tid = threadIdx.x;
  int wvv = tid >> 6, lane = tid & 63;
  int quad = lane >> 4, l16 = lane & 15;
  int mw = m0 + wvv * 32;
  const short* ap0 = Abf + (size_t)(mw + l16) * 512 + quad * 8;
  const short* ap1 = ap0 + 16 * 512;
  const short* bp = Wbf + (size_t)(n0 + l16) * 512 + quad * 8;
  f32x4 acc[2][4] = {};
  bf16x8 cA0 = *(const bf16x8*)ap0;
  bf16x8 cA1 = *(const bf16x8*)ap1;
  bf16x8 cB0 = *(const bf16x8*)(bp + 0 * 16 * 512);
  bf16x8 cB1 = *(const bf16x8*)(bp + 1 * 16 * 512);
  bf16x8 cB2 = *(const bf16x8*)(bp + 2 * 16 * 512);
  bf16x8 cB3 = *(const bf16x8*)(bp + 3 * 16 * 512);
#pragma unroll 2
  for (int ks = 0; ks < 16; ks++) {
    int offn = (ks + 1 < 16 ? ks + 1 : 15) * 32;
    bf16x8 nA0 = *(const bf16x8*)(ap0 + offn);
    bf16x8 nA1 = *(const bf16x8*)(ap1 + offn);
    bf16x8 nB0 = *(const bf16x8*)(bp + 0 * 16 * 512 + offn);
    bf16x8 nB1 = *(const bf16x8*)(bp + 1 * 16 * 512 + offn);
    bf16x8 nB2 = *(const bf16x8*)(bp + 2 * 16 * 512 + offn);
    bf16x8 nB3 = *(const bf16x8*)(bp + 3 * 16 * 512 + offn);
    acc[0][0] = __builtin_amdgcn_mfma_f32_16x16x32_bf16(cA0, cB0, acc[0][0], 0, 0, 0);
    acc[1][0] = __builtin_amdgcn_mfma_f32_16x16x32_bf16(cA1, cB0, acc[1][0], 0, 0, 0);
    acc[0][1] = __builtin_amdgcn_mfma_f32_16x16x32_bf16(cA0, cB1, acc[0][1], 0, 0, 0);
    acc[1][1] = __builtin_amdgcn_mfma_f32_16x16x32_bf16(cA1, cB1, acc[1][1], 0, 0, 0);
    acc[0][2] = __builtin_amdgcn_mfma_f32_16x16x32_bf16(cA0, cB2, acc[0][2], 0, 0, 0);
    acc[1][2] = __builtin_amdgcn_mfma_f32_16x16x32_bf16(cA1, cB2, acc[1][2], 0, 0, 0);
    acc[0][3] = __builtin_amdgcn_mfma_f32_16x16x32_bf16(cA0, cB3, acc[0][3], 0, 0, 0);
    acc[1][3] = __builtin_amdgcn_mfma_f32_16x16x32_bf16(cA1, cB3, acc[1][3], 0, 0, 0);
    cA0 = nA0; cA1 = nA1;
    cB0 = nB0; cB1 = nB1; cB2 = nB2; cB3 = nB3;
  }
#pragma unroll
  for (int mt = 0; mt < 2; mt++) {
#pragma unroll
    for (int r = 0; r < 4; r++) {
      int m = mw + mt * 16 + quad * 4 + r;
#pragma unroll
      for (int t = 0; t < 4; t++) {
        int n = n0 + t * 16 + l16;
        outp[(size_t)m * 512 + n] =
            acc[mt][t][r] + bo[n] + bf2f(hbf[(size_t)m * 512 + n]);
      }
    }
  }
}

// ---------------------------------------------------------------------------
// layernorm in place on d_out, one block per row
// ---------------------------------------------------------------------------
__global__ __launch_bounds__(256) void ln_kernel(float* __restrict__ o,
                                                 const float* __restrict__ g,
                                                 const float* __restrict__ bb) {
  int row = blockIdx.x;
  int tid = threadIdx.x;
  float v0 = o[row * 512 + tid];
  float v1 = o[row * 512 + 256 + tid];
  float s = v0 + v1;
  float s2 = v0 * v0 + v1 * v1;
#pragma unroll
  for (int off = 1; off < 64; off <<= 1) {
    s += __shfl_xor(s, off);
    s2 += __shfl_xor(s2, off);
  }
  __shared__ float ps[4], ps2[4];
  int w = tid >> 6;
  if ((tid & 63) == 0) { ps[w] = s; ps2[w] = s2; }
  __syncthreads();
  float S = ps[0] + ps[1] + ps[2] + ps[3];
  float S2 = ps2[0] + ps2[1] + ps2[2] + ps2[3];
  float mu = S * (1.f / 512.f);
  float var = S2 * (1.f / 512.f) - mu * mu;
  float inv = rsqrtf(var + 1e-5f);
  o[row * 512 + tid] = (v0 - mu) * inv * g[tid] + bb[tid];
  o[row * 512 + 256 + tid] = (v1 - mu) * inv * g[tid + 256] + bb[tid + 256];
}

// ---------------------------------------------------------------------------
extern "C" void kernel_launch(void* const* d_in, const int* in_sizes, int n_in,
                              void* d_out, int out_size, void* d_ws,
                              size_t ws_size, hipStream_t stream) {
  const float* x   = (const float*)d_in[0];
  const float* w1  = (const float*)d_in[1];
  const float* b1  = (const float*)d_in[2];
  const float* w2  = (const float*)d_in[3];
  const float* b2  = (const float*)d_in[4];
  const float* w3  = (const float*)d_in[5];
  const float* b3  = (const float*)d_in[6];
  const float* Wq  = (const float*)d_in[7];
  const float* bq  = (const float*)d_in[8];
  const float* Wk  = (const float*)d_in[9];
  const float* bk  = (const float*)d_in[10];
  const float* Wv  = (const float*)d_in[11];
  const float* bv  = (const float*)d_in[12];
  const float* Wkp = (const float*)d_in[13];
  const float* bkp = (const float*)d_in[14];
  const float* Wvp = (const float*)d_in[15];
  const float* bvp = (const float*)d_in[16];
  const float* Wo  = (const float*)d_in[17];
  const float* bo  = (const float*)d_in[18];
  const float* lng = (const float*)d_in[19];
  const float* lnb = (const float*)d_in[20];

  float* p = (float*)d_ws;
  short* Wallbf = (short*)p;  p += 786432;
  float* ball   = p;          p += 2048;
  short* Wobf   = (short*)p;  p += 262144;
  short* Wkpbf  = (short*)p;  p += 4096;
  short* W2bf   = (short*)p;  p += 4096;
  float* cvec   = p;          p += 64;
  short* hbf    = (short*)p;  p += 1048576;
  short* Qh     = (short*)p;  p += 1048576;
  short* Kh     = (short*)p;  p += 1048576;
  short* Vh     = (short*)p;  p += 1048576;
  short* Kph    = (short*)p;  p += 1048576;
  float* Vpp    = p;          p += 2097152;
  float* ctxl   = p;          p += 2097152;
  short* ctxcb  = (short*)p;  p += 1048576;
  float* outF   = (float*)d_out;

  conv_prep_kernel<<<768, 256, 0, stream>>>(
      x, w1, b1, w2, b2, w3, b3, hbf, Wq, Wk, Wv, bq, bk, bv, Wo, Wkp, Wvp,
      bvp, Wallbf, ball, Wobf, Wkpbf, W2bf, cvec);
  {
    dim3 g(32, 24);
    gemm_qkv<<<g, 256, 0, stream>>>(hbf, Wallbf, ball, Qh, Kh, Vh);
  }
  kpvp_local_kernel<<<768, 256, 0, stream>>>(Kh, Vh, Wkpbf, bkp, W2bf, cvec,
                                             Kph, Vpp, Qh, ctxl);
  global_attn<<<1024, 256, 0, stream>>>(Qh, Kph, Vpp, ctxl, ctxcb);
  {
    dim3 g(32, 8);
    gemm_wo<<<g, 256, 0, stream>>>(ctxcb, Wobf, bo, hbf, outF);
  }
  ln_kernel<<<4096, 256, 0, stream>>>(outF, lng, lnb);
}

// Round 8
// 271.889 us; speedup vs baseline: 1.0769x; 1.0769x over previous
//
#include <hip/hip_runtime.h>
#include <hip/hip_bf16.h>

#define BB 2
#define SS 2048
#define INC 64
#define HIDN 512
#define NHH 8
#define HDD 64

typedef __attribute__((ext_vector_type(8))) short bf16x8;
typedef __attribute__((ext_vector_type(4))) float f32x4;

__device__ __forceinline__ short f2bf(float f) {
  union { __hip_bfloat16 h; short s; } u;
  u.h = __float2bfloat16(f);
  return u.s;
}
__device__ __forceinline__ float bf2f(short s) {
  return __uint_as_float(((unsigned)(unsigned short)s) << 16);
}

// ---------------------------------------------------------------------------
// conv + prep fused (independent work, one launch).
// ---------------------------------------------------------------------------
template <int KW, int OFF>
__device__ __forceinline__ void conv_channel(const float* __restrict__ w,
                                             const float* xs, float bias,
                                             float acc[8]) {
#pragma unroll
  for (int i = 0; i < 8; i++) acc[i] = bias;
#pragma unroll 4
  for (int ci = 0; ci < 64; ci++) {
    float xv[8 + KW - 1];
#pragma unroll
    for (int r = 0; r < 8 + KW - 1; r++) xv[r] = xs[(r + OFF) * 64 + ci];
#pragma unroll
    for (int k = 0; k < KW; k++) {
      float wv = w[ci * KW + k];
#pragma unroll
      for (int i = 0; i < 8; i++) acc[i] += xv[i + k] * wv;
    }
  }
}

__global__ __launch_bounds__(256) void conv_prep_kernel(
    const float* __restrict__ x, const float* __restrict__ w1,
    const float* __restrict__ b1, const float* __restrict__ w2,
    const float* __restrict__ b2, const float* __restrict__ w3,
    const float* __restrict__ b3, short* __restrict__ hbf,
    const float* __restrict__ Wq, const float* __restrict__ Wk_,
    const float* __restrict__ Wv_, const float* __restrict__ bq,
    const float* __restrict__ bk_, const float* __restrict__ bv_,
    const float* __restrict__ Wo, const float* __restrict__ Wkp,
    const float* __restrict__ Wvp, const float* __restrict__ bvp,
    short* __restrict__ Wallbf, float* __restrict__ ball,
    short* __restrict__ Wobf, short* __restrict__ Wkpbf,
    short* __restrict__ W2bf, float* __restrict__ cvec) {
  const int TS = 8;
  __shared__ float xs[(TS + 6) * 64];
  int tid = threadIdx.x;
  if (blockIdx.x < 512) {
    int blk = blockIdx.x;
    int b = blk / (SS / TS);
    int s0 = (blk % (SS / TS)) * TS;
    for (int i = tid; i < (TS + 6) * 64; i += 256) {
      int row = i >> 6, ci = i & 63;
      int sgl = s0 + row - 3;
      xs[i] = (sgl >= 0 && sgl < SS) ? x[(b * SS + sgl) * 64 + ci] : 0.f;
    }
    __syncthreads();
    for (int c = tid; c < 512; c += 256) {
      float acc[8];
      if (c < 171) {
        conv_channel<3, 2>(w1 + c * (64 * 3), xs, b1[c], acc);
      } else if (c < 342) {
        conv_channel<5, 1>(w2 + (c - 171) * (64 * 5), xs, b2[c - 171], acc);
      } else {
        conv_channel<7, 0>(w3 + (c - 342) * (64 * 7), xs, b3[c - 342], acc);
      }
#pragma unroll
      for (int i = 0; i < 8; i++) {
        float v = fmaxf(acc[i], 0.f);
        hbf[(b * SS + s0 + i) * 512 + c] = f2bf(v);
      }
    }
  } else {
    int i0 = (blockIdx.x - 512) * 256 + tid;
    int stride = 256 * 256;
    for (int idx = i0; idx < 786432; idx += stride) {
      float v;
      if (idx < 262144)      v = Wq[idx];
      else if (idx < 524288) v = Wk_[idx - 262144];
      else                   v = Wv_[idx - 524288];
      Wallbf[idx] = f2bf(v);
    }
    for (int idx = i0; idx < 262144; idx += stride) Wobf[idx] = f2bf(Wo[idx]);
    for (int idx = i0; idx < 4096; idx += stride) {
      Wkpbf[idx] = f2bf(Wkp[idx]);
      int j = idx >> 6, d = idx & 63;
      float s = 0.f;
#pragma unroll 8
      for (int i = 0; i < 64; i++) s += Wvp[j * 64 + i] * Wvp[i * 64 + d];
      W2bf[idx] = f2bf(s);
    }
    if (i0 < 1536) {
      float v;
      if (i0 < 512)       v = bq[i0];
      else if (i0 < 1024) v = bk_[i0 - 512];
      else                v = bv_[i0 - 1024];
      ball[i0] = v;
    }
    if (i0 < 64) {
      float s = bvp[i0];
#pragma unroll 8
      for (int i = 0; i < 64; i++) s += bvp[i] * Wvp[i0 * 64 + i];
      cvec[i0] = s;
    }
  }
}

// ---------------------------------------------------------------------------
// MFMA QKV gemm: 128-row blocks, wave = 32 rows x 64 cols.
// ---------------------------------------------------------------------------
__global__ __launch_bounds__(256, 4) void gemm_qkv(
    const short* __restrict__ Abf, const short* __restrict__ Wbf,
    const float* __restrict__ bias, short* __restrict__ Qh,
    short* __restrict__ Kh, short* __restrict__ Vh) {
  int m0 = blockIdx.x * 128;
  int n0 = blockIdx.y * 64;
  int tid = threadIdx.x;
  int wvv = tid >> 6, lane = tid & 63;
  int quad = lane >> 4, l16 = lane & 15;
  int mw = m0 + wvv * 32;
  const short* ap0 = Abf + (size_t)(mw + l16) * 512 + quad * 8;
  const short* ap1 = ap0 + 16 * 512;
  const short* bp = Wbf + (size_t)(n0 + l16) * 512 + quad * 8;
  f32x4 acc[2][4] = {};
  bf16x8 cA0 = *(const bf16x8*)ap0;
  bf16x8 cA1 = *(const bf16x8*)ap1;
  bf16x8 cB0 = *(const bf16x8*)(bp + 0 * 16 * 512);
  bf16x8 cB1 = *(const bf16x8*)(bp + 1 * 16 * 512);
  bf16x8 cB2 = *(const bf16x8*)(bp + 2 * 16 * 512);
  bf16x8 cB3 = *(const bf16x8*)(bp + 3 * 16 * 512);
#pragma unroll 2
  for (int ks = 0; ks < 16; ks++) {
    int offn = (ks + 1 < 16 ? ks + 1 : 15) * 32;
    bf16x8 nA0 = *(const bf16x8*)(ap0 + offn);
    bf16x8 nA1 = *(const bf16x8*)(ap1 + offn);
    bf16x8 nB0 = *(const bf16x8*)(bp + 0 * 16 * 512 + offn);
    bf16x8 nB1 = *(const bf16x8*)(bp + 1 * 16 * 512 + offn);
    bf16x8 nB2 = *(const bf16x8*)(bp + 2 * 16 * 512 + offn);
    bf16x8 nB3 = *(const bf16x8*)(bp + 3 * 16 * 512 + offn);
    acc[0][0] = __builtin_amdgcn_mfma_f32_16x16x32_bf16(cA0, cB0, acc[0][0], 0, 0, 0);
    acc[1][0] = __builtin_amdgcn_mfma_f32_16x16x32_bf16(cA1, cB0, acc[1][0], 0, 0, 0);
    acc[0][1] = __builtin_amdgcn_mfma_f32_16x16x32_bf16(cA0, cB1, acc[0][1], 0, 0, 0);
    acc[1][1] = __builtin_amdgcn_mfma_f32_16x16x32_bf16(cA1, cB1, acc[1][1], 0, 0, 0);
    acc[0][2] = __builtin_amdgcn_mfma_f32_16x16x32_bf16(cA0, cB2, acc[0][2], 0, 0, 0);
    acc[1][2] = __builtin_amdgcn_mfma_f32_16x16x32_bf16(cA1, cB2, acc[1][2], 0, 0, 0);
    acc[0][3] = __builtin_amdgcn_mfma_f32_16x16x32_bf16(cA0, cB3, acc[0][3], 0, 0, 0);
    acc[1][3] = __builtin_amdgcn_mfma_f32_16x16x32_bf16(cA1, cB3, acc[1][3], 0, 0, 0);
    cA0 = nA0; cA1 = nA1;
    cB0 = nB0; cB1 = nB1; cB2 = nB2; cB3 = nB3;
  }
  int which = n0 >> 9;
  int head = (n0 >> 6) & 7;
  short* dst = which == 0 ? Qh : (which == 1 ? Kh : Vh);
  float scale = which == 0 ? 0.125f : 1.0f;
#pragma unroll
  for (int mt = 0; mt < 2; mt++) {
#pragma unroll
    for (int r = 0; r < 4; r++) {
      int m = mw + mt * 16 + quad * 4 + r;
      int bb = m >> 11, s = m & 2047;
      size_t rowoff = ((size_t)(bb * 8 + head) * 2048 + s) * 64;
#pragma unroll
      for (int t = 0; t < 4; t++) {
        int hd = t * 16 + l16;
        float v = acc[mt][t][r] + bias[n0 + hd];
        dst[rowoff + hd] = f2bf(v * scale);
      }
    }
  }
}

// ---------------------------------------------------------------------------
// kpvp + local_attn fused.
// ---------------------------------------------------------------------------
__global__ __launch_bounds__(256, 4) void kpvp_local_kernel(
    const short* __restrict__ Kh, const short* __restrict__ Vh,
    const short* __restrict__ Wkpbf, const float* __restrict__ bkp,
    const short* __restrict__ W2bf, const float* __restrict__ cvec,
    short* __restrict__ Kph, float* __restrict__ Vpp,
    const short* __restrict__ Qh, float* __restrict__ ctxl) {
  int tid = threadIdx.x;
  __shared__ float Sloc[4][2][16][17];
  __shared__ float wloc[4][16][8];
  if (blockIdx.x < 256) {
    int m0 = blockIdx.x * 128;
    int wvv = tid >> 6, lane = tid & 63;
    int quad = lane >> 4, l16 = lane & 15;
    int mw = m0 + wvv * 32;
    {
      const short* ap0 = Kh + (size_t)(mw + l16) * 64 + quad * 8;
      const short* ap1 = ap0 + 16 * 64;
      const short* bp = Wkpbf + l16 * 64 + quad * 8;
      bf16x8 A00 = *(const bf16x8*)ap0, A01 = *(const bf16x8*)(ap0 + 32);
      bf16x8 A10 = *(const bf16x8*)ap1, A11 = *(const bf16x8*)(ap1 + 32);
      f32x4 acc[2][4] = {};
#pragma unroll
      for (int t = 0; t < 4; t++) {
        bf16x8 B0 = *(const bf16x8*)(bp + t * 16 * 64);
        bf16x8 B1 = *(const bf16x8*)(bp + t * 16 * 64 + 32);
        acc[0][t] = __builtin_amdgcn_mfma_f32_16x16x32_bf16(A00, B0, acc[0][t], 0, 0, 0);
        acc[0][t] = __builtin_amdgcn_mfma_f32_16x16x32_bf16(A01, B1, acc[0][t], 0, 0, 0);
        acc[1][t] = __builtin_amdgcn_mfma_f32_16x16x32_bf16(A10, B0, acc[1][t], 0, 0, 0);
        acc[1][t] = __builtin_amdgcn_mfma_f32_16x16x32_bf16(A11, B1, acc[1][t], 0, 0, 0);
      }
#pragma unroll
      for (int mt = 0; mt < 2; mt++)
#pragma unroll
        for (int r = 0; r < 4; r++) {
          int m = mw + mt * 16 + quad * 4 + r;
#pragma unroll
          for (int t = 0; t < 4; t++) {
            int n = t * 16 + l16;
            Kph[(size_t)m * 64 + n] = f2bf(acc[mt][t][r] + bkp[n]);
          }
        }
    }
    {
      const short* ap0 = Vh + (size_t)(mw + l16) * 64 + quad * 8;
      const short* ap1 = ap0 + 16 * 64;
      const short* bp = W2bf + l16 * 64 + quad * 8;
      bf16x8 A00 = *(const bf16x8*)ap0, A01 = *(const bf16x8*)(ap0 + 32);
      bf16x8 A10 = *(const bf16x8*)ap1, A11 = *(const bf16x8*)(ap1 + 32);
      f32x4 acc[2][4] = {};
#pragma unroll
      for (int t = 0; t < 4; t++) {
        bf16x8 B0 = *(const bf16x8*)(bp + t * 16 * 64);
        bf16x8 B1 = *(const bf16x8*)(bp + t * 16 * 64 + 32);
        acc[0][t] = __builtin_amdgcn_mfma_f32_16x16x32_bf16(A00, B0, acc[0][t], 0, 0, 0);
        acc[0][t] = __builtin_amdgcn_mfma_f32_16x16x32_bf16(A01, B1, acc[0][t], 0, 0, 0);
        acc[1][t] = __builtin_amdgcn_mfma_f32_16x16x32_bf16(A10, B0, acc[1][t], 0, 0, 0);
        acc[1][t] = __builtin_amdgcn_mfma_f32_16x16x32_bf16(A11, B1, acc[1][t], 0, 0, 0);
      }
#pragma unroll
      for (int mt = 0; mt < 2; mt++)
#pragma unroll
        for (int r = 0; r < 4; r++) {
          int m = mw + mt * 16 + quad * 4 + r;
#pragma unroll
          for (int t = 0; t < 4; t++) {
            int n = t * 16 + l16;
            Vpp[(size_t)m * 64 + n] = acc[mt][t][r] + cvec[n];
          }
        }
    }
    return;
  }
  // ---- local windowed attention ----
  int wv = tid >> 6;
  int tile = (blockIdx.x - 256) * 4 + wv;   // 0..2047
  int bh = tile >> 7;
  int q0 = (tile & 127) * 16;
  int lane = tid & 63;
  int quad = lane >> 4, l16 = lane & 15;

  const short* qbase = Qh + (size_t)(bh * 2048 + q0 + l16) * 64 + quad * 8;
  bf16x8 a0 = *(const bf16x8*)qbase;
  bf16x8 a1 = *(const bf16x8*)(qbase + 32);

  int k0a = min(max(q0 - 2 + l16, 0), 2047);
  int k1a = min(q0 + 6 + l16, 2047);
  const short* kb0 = Kh + (size_t)(bh * 2048 + k0a) * 64 + quad * 8;
  const short* kb1 = Kh + (size_t)(bh * 2048 + k1a) * 64 + quad * 8;
  bf16x8 B00 = *(const bf16x8*)kb0;
  bf16x8 B01 = *(const bf16x8*)(kb0 + 32);
  bf16x8 B10 = *(const bf16x8*)kb1;
  bf16x8 B11 = *(const bf16x8*)(kb1 + 32);
  f32x4 C0 = {0.f, 0.f, 0.f, 0.f};
  f32x4 C1 = {0.f, 0.f, 0.f, 0.f};
  C0 = __builtin_amdgcn_mfma_f32_16x16x32_bf16(a0, B00, C0, 0, 0, 0);
  C0 = __builtin_amdgcn_mfma_f32_16x16x32_bf16(a1, B01, C0, 0, 0, 0);
  C1 = __builtin_amdgcn_mfma_f32_16x16x32_bf16(a0, B10, C1, 0, 0, 0);
  C1 = __builtin_amdgcn_mfma_f32_16x16x32_bf16(a1, B11, C1, 0, 0, 0);
#pragma unroll
  for (int r = 0; r < 4; r++) {
    Sloc[wv][0][quad * 4 + r][l16] = C0[r];
    Sloc[wv][1][quad * 4 + r][l16] = C1[r];
  }
  __builtin_amdgcn_wave_barrier();
  if (lane < 16) {
    int q = lane;
    float sc[5];
    bool ok[5];
#pragma unroll
    for (int j = 0; j < 5; j++) {
      int offq = q + j - 2;
      int sg = q0 + offq;
      ok[j] = (sg >= 0 && sg < SS);
      int t = offq <= 13 ? 0 : 1;
      int col = t ? offq - 6 : offq + 2;
      sc[j] = ok[j] ? Sloc[wv][t][q][col] : -3.0e38f;
    }
    float m = -3.0e38f;
#pragma unroll
    for (int j = 0; j < 5; j++) m = fmaxf(m, sc[j]);
    float e[5], l = 0.f;
#pragma unroll
    for (int j = 0; j < 5; j++) {
      e[j] = ok[j] ? __expf(sc[j] - m) : 0.f;
      l += e[j];
    }
    float inv = 1.f / l;
#pragma unroll
    for (int j = 0; j < 5; j++) wloc[wv][q][j] = e[j] * inv;
  }
  __builtin_amdgcn_wave_barrier();
  {
    int q = lane >> 2, jb = (lane & 3) * 16;
    int s = q0 + q;
    float acc[16] = {};
#pragma unroll
    for (int j = 0; j < 5; j++) {
      int sg = s + j - 2;
      if (sg >= 0 && sg < SS) {
        float w = wloc[wv][q][j];
        const short* vr = Vh + (size_t)(bh * 2048 + sg) * 64 + jb;
#pragma unroll
        for (int u = 0; u < 16; u += 4) {
          short4 v4 = *(const short4*)(vr + u);
          acc[u + 0] += w * bf2f(v4.x);
          acc[u + 1] += w * bf2f(v4.y);
          acc[u + 2] += w * bf2f(v4.z);
          acc[u + 3] += w * bf2f(v4.w);
        }
      }
    }
    float* orow = ctxl + (size_t)(bh * 2048 + s) * 64 + jb;
#pragma unroll
    for (int u = 0; u < 16; u += 4)
      *(float4*)(orow + u) =
          make_float4(acc[u], acc[u + 1], acc[u + 2], acc[u + 3]);
  }
}

// ---------------------------------------------------------------------------
// global sparse attention — v8: LDS-STAGED K PANEL, one block per CU.
// Theory (r7 post-mortem): 82us floor = per-CU L1-miss throughput — 16
// waves/CU each independently stream the same 256KB Kph panel with loads
// whose 64 lanes stride 16 cache lines each; L1 (32KB) can't hold the
// panel, so per-CU line-misses x L2 latency / outstanding-miss-depth ~= 82us,
// insensitive to occupancy/VALU/prefetch/XCD (all confirmed null).
// Fix: grid 256 (1 block/CU), 512 threads = 8 waves; block = 8 tiles of one
// bh. K panel streams ONCE per CU through double-buffered LDS chunks
// (coalesced 32B/thread loads), waves consume via XOR-swizzled ds_read_b128.
// Each wave owns a full tile (2048 keys, depth-8 lists = round-1-verified
// selection); no cross-wave merge.
// ---------------------------------------------------------------------------
__global__ __launch_bounds__(512, 1) void global_attn(
    const short* __restrict__ Qh, const short* __restrict__ Kph,
    const float* __restrict__ Vpp, const float* __restrict__ ctxl,
    short* __restrict__ ctxcb) {
  int tid = threadIdx.x;
  int wv = tid >> 6;
  int lane = tid & 63;
  int quad = lane >> 4, l16 = lane & 15;
  int p = blockIdx.x;                       // 0..255
  int bh = (p & 7) * 2 + ((p >> 3) & 1);    // XCD-affine
  int seg = p >> 4;                         // 0..15
  int tile = seg * 8 + wv;                  // tile within bh: 0..127
  int q0 = tile * 16;

  __shared__ short Ks[2][128][64];          // 32 KB, col-swizzled
  __shared__ float twl[8][16][17];
  __shared__ int   txl[8][16][17];

  const short* qbase = Qh + (size_t)(bh * 2048 + q0 + l16) * 64 + quad * 8;
  bf16x8 a0 = *(const bf16x8*)qbase;
  bf16x8 a1 = *(const bf16x8*)(qbase + 32);

  const short* kpanel = Kph + (size_t)bh * (2048 * 64);

  unsigned er[4][8];
#pragma unroll
  for (int a = 0; a < 4; a++)
#pragma unroll
    for (int j = 0; j < 8; j++) er[a][j] = 0u;

  // med3 sorted-insert: depth-1, 8 ops.
  auto insert8 = [&](unsigned (&e)[8], unsigned cand) {
    unsigned n0, n1, n2, n3, n4, n5, n6, n7;
    asm("v_max_u32 %0, %1, %2" : "=v"(n0) : "v"(e[0]), "v"(cand));
    asm("v_med3_u32 %0, %1, %2, %3" : "=v"(n1) : "v"(e[0]), "v"(e[1]), "v"(cand));
    asm("v_med3_u32 %0, %1, %2, %3" : "=v"(n2) : "v"(e[1]), "v"(e[2]), "v"(cand));
    asm("v_med3_u32 %0, %1, %2, %3" : "=v"(n3) : "v"(e[2]), "v"(e[3]), "v"(cand));
    asm("v_med3_u32 %0, %1, %2, %3" : "=v"(n4) : "v"(e[3]), "v"(e[4]), "v"(cand));
    asm("v_med3_u32 %0, %1, %2, %3" : "=v"(n5) : "v"(e[4]), "v"(e[5]), "v"(cand));
    asm("v_med3_u32 %0, %1, %2, %3" : "=v"(n6) : "v"(e[5]), "v"(e[6]), "v"(cand));
    asm("v_med3_u32 %0, %1, %2, %3" : "=v"(n7) : "v"(e[6]), "v"(e[7]), "v"(cand));
    e[0] = n0; e[1] = n1; e[2] = n2; e[3] = n3;
    e[4] = n4; e[5] = n5; e[6] = n6; e[7] = n7;
  };
  auto mkcand = [&](float s, int idxr) -> unsigned {
    unsigned u = __float_as_uint(s);
    u ^= ((unsigned)((int)u >> 31)) | 0x80000000u;
    return (u & 0xFFFFF800u) | (unsigned)idxr;
  };

  // Staging: thread t covers 32B of the 16KB chunk (coalesced).
  int skey = tid >> 2;                  // 0..127
  int scol = (tid & 3) * 16;            // shorts
  int ssw = (skey & 7) << 3;            // swizzle (shorts)
  const short* gsrc = kpanel + (size_t)tid * 16;

  bf16x8 c0 = *(const bf16x8*)gsrc;
  bf16x8 c1 = *(const bf16x8*)(gsrc + 8);
  {
    short* dst = &Ks[0][skey][0];
    *(bf16x8*)(dst + (scol ^ ssw)) = c0;
    *(bf16x8*)(dst + ((scol + 8) ^ ssw)) = c1;
  }
  __syncthreads();

  int rsw = ((l16 & 7) << 3);           // read swizzle base for row l16
#pragma unroll 1
  for (int ck = 0; ck < 16; ck++) {
    int cb = ck & 1, nb = cb ^ 1;
    bf16x8 p0, p1;
    if (ck < 15) {
      const short* ng = kpanel + (size_t)(ck + 1) * 8192 + tid * 16;
      p0 = *(const bf16x8*)ng;
      p1 = *(const bf16x8*)(ng + 8);
    }
    // consume chunk ck: 128 keys in 4 double-groups of 32.
#pragma unroll
    for (int gg = 0; gg < 4; gg++) {
      int k0 = gg * 32 + l16;           // first 16-key group row
      int k1 = k0 + 16;
      const short* s0 = &Ks[cb][k0][0];
      const short* s1 = &Ks[cb][k1][0];
      bf16x8 B00 = *(const bf16x8*)(s0 + ((quad * 8) ^ rsw));
      bf16x8 B01 = *(const bf16x8*)(s0 + ((quad * 8 + 32) ^ rsw));
      bf16x8 B10 = *(const bf16x8*)(s1 + ((quad * 8) ^ rsw));
      bf16x8 B11 = *(const bf16x8*)(s1 + ((quad * 8 + 32) ^ rsw));
      f32x4 C0 = {0.f, 0.f, 0.f, 0.f};
      f32x4 C1 = {0.f, 0.f, 0.f, 0.f};
      C0 = __builtin_amdgcn_mfma_f32_16x16x32_bf16(a0, B00, C0, 0, 0, 0);
      C0 = __builtin_amdgcn_mfma_f32_16x16x32_bf16(a1, B01, C0, 0, 0, 0);
      C1 = __builtin_amdgcn_mfma_f32_16x16x32_bf16(a0, B10, C1, 0, 0, 0);
      C1 = __builtin_amdgcn_mfma_f32_16x16x32_bf16(a1, B11, C1, 0, 0, 0);
      int idxr0 = 2047 - (ck * 128 + gg * 32) - l16;
      int idxr1 = idxr0 - 16;
      insert8(er[0], mkcand(C0[0], idxr0));
      insert8(er[1], mkcand(C0[1], idxr0));
      insert8(er[2], mkcand(C0[2], idxr0));
      insert8(er[3], mkcand(C0[3], idxr0));
      insert8(er[0], mkcand(C1[0], idxr1));
      insert8(er[1], mkcand(C1[1], idxr1));
      insert8(er[2], mkcand(C1[2], idxr1));
      insert8(er[3], mkcand(C1[3], idxr1));
    }
    __syncthreads();                    // buf[nb]'s previous consumers done
    if (ck < 15) {
      short* dst = &Ks[nb][skey][0];
      *(bf16x8*)(dst + (scol ^ ssw)) = p0;
      *(bf16x8*)(dst + ((scol + 8) ^ ssw)) = p1;
      __syncthreads();                  // buf[nb] ready
    }
  }

  // Extraction + inline softmax (round-1 verified form): per wave, pop the
  // global top-16 per query from the 16 lanes' depth-8 lists; every lane
  // redundantly tracks lsum.
  {
    float mval[4] = {0.f, 0.f, 0.f, 0.f};
    float lsum[4] = {0.f, 0.f, 0.f, 0.f};
    float myev[4] = {0.f, 0.f, 0.f, 0.f};
    int myki[4] = {0, 0, 0, 0};
#pragma unroll
    for (int t = 0; t < 16; t++) {
#pragma unroll
      for (int a = 0; a < 4; a++) {
        unsigned w = er[a][0];
#pragma unroll
        for (int mm = 1; mm <= 8; mm <<= 1) {
          unsigned o = (unsigned)__shfl_xor((int)w, mm);
          w = w > o ? w : o;
        }
        bool pop = (er[a][0] == w);
#pragma unroll
        for (int j = 0; j < 7; j++) er[a][j] = pop ? er[a][j + 1] : er[a][j];
        er[a][7] = pop ? 0u : er[a][7];
        unsigned wb = w & 0xFFFFF800u;
        unsigned uu = (w & 0x80000000u) ? (wb ^ 0x80000000u) : ~wb;
        float sv = (w == 0u) ? -1.0e30f : __uint_as_float(uu);
        if (t == 0) mval[a] = sv;
        float ex = __expf(sv - mval[a]);
        lsum[a] += ex;
        if (l16 == t) { myev[a] = ex; myki[a] = 2047 - (int)(w & 0x7FFu); }
      }
    }
#pragma unroll
    for (int a = 0; a < 4; a++) {
      twl[wv][quad * 4 + a][l16] = myev[a] / lsum[a];
      txl[wv][quad * 4 + a][l16] = myki[a];
    }
  }
  __builtin_amdgcn_wave_barrier();

  // Per-wave weighted gather of prefolded Vpp rows; combine with local ctx.
  {
    int q = lane >> 2, d0 = (lane & 3) * 16;
    int b = bh >> 3, hh = bh & 7;
    const float* vball = Vpp + (size_t)bh * (2048 * 64) + d0;
    float acc[16];
#pragma unroll
    for (int u = 0; u < 16; u++) acc[u] = 0.f;
#pragma unroll 4
    for (int j = 0; j < 16; j++) {
      float w = twl[wv][q][j];
      const float* vr = vball + (size_t)txl[wv][q][j] * 64;
#pragma unroll
      for (int u = 0; u < 16; u += 4) {
        float4 v = *(const float4*)(vr + u);
        acc[u + 0] += w * v.x;
        acc[u + 1] += w * v.y;
        acc[u + 2] += w * v.z;
        acc[u + 3] += w * v.w;
      }
    }
    int s = q0 + q;
    const float* lrow = ctxl + (size_t)(bh * 2048 + s) * 64 + d0;
    short* orow = ctxcb + (size_t)(b * 2048 + s) * 512 + hh * 64 + d0;
#pragma unroll
    for (int u = 0; u < 16; u += 4) {
      float4 lv = *(const float4*)(lrow + u);
      short4 o;
      o.x = f2bf(0.5f * (lv.x + acc[u + 0]));
      o.y = f2bf(0.5f * (lv.y + acc[u + 1]));
      o.z = f2bf(0.5f * (lv.z + acc[u + 2]));
      o.w = f2bf(0.5f * (lv.w + acc[u + 3]));
      *(short4*)(orow + u) = o;
    }
  }
}

// ---------------------------------------------------------------------------
// MFMA Wo gemm: 128-row blocks, wave = 32 rows. Residual from bf16 hbf.
// ---------------------------------------------------------------------------
__global__ __launch_bounds__(256, 4) void gemm_wo(
    const short* __restrict__ Abf, const short* __restrict__ Wbf,
    const float* __restrict__ bo, const short* __restrict__ hbf,
    float* __restrict__ outp) {
  int m0 = blockIdx.x * 128;
  int n0 = blockIdx.y * 64;
  int tid = threadIdx.x;
  int wvv = tid >> 6, lane = tid & 63;
  int quad = lane >> 4, l16 = lane & 15;
  int mw = m0 + wvv * 32;
  const short* ap0 = Abf + (size_t)(mw + l16) * 512 + quad * 8;
  const short* ap1 = ap0 + 16 * 512;
  const short* bp = Wbf + (size_t)(n0 + l16) * 512 + quad * 8;
  f32x4 acc[2][4] = {};
  bf16x8 cA0 = *(const bf16x8*)ap0;
  bf16x8 cA1 = *(const bf16x8*)ap1;
  bf16x8 cB0 = *(const bf16x8*)(bp + 0 * 16 * 512);
  bf16x8 cB1 = *(const bf16x8*)(bp + 1 * 16 * 512);
  bf16x8 cB2 = *(const bf16x8*)(bp + 2 * 16 * 512);
  bf16x8 cB3 = *(const bf16x8*)(bp + 3 * 16 * 512);
#pragma unroll 2
  for (int ks = 0; ks < 16; ks++) {
    int offn = (ks + 1 < 16 ? ks + 1 : 15) * 32;
    bf16x8 nA0 = *(const bf16x8*)(ap0 + offn);
    bf16x8 nA1 = *(const bf16x8*)(ap1 + offn);
    bf16x8 nB0 = *(const bf16x8*)(bp + 0 * 16 * 512 + offn);
    bf16x8 nB1 = *(const bf16x8*)(bp + 1 * 16 * 512 + offn);
    bf16x8 nB2 = *(const bf16x8*)(bp + 2 * 16 * 512 + offn);
    bf16x8 nB3 = *(const bf16x8*)(bp + 3 * 16 * 512 + offn);
    acc[0][0] = __builtin_amdgcn_mfma_f32_16x16x32_bf16(cA0, cB0, acc[0][0], 0, 0, 0);
    acc[1][0] = __builtin_amdgcn_mfma_f32_16x16x32_bf16(cA1, cB0, acc[1][0], 0, 0, 0);
    acc[0][1] = __builtin_amdgcn_mfma_f32_16x16x32_bf16(cA0, cB1, acc[0][1], 0, 0, 0);
    acc[1][1] = __builtin_amdgcn_mfma_f32_16x16x32_bf16(cA1, cB1, acc[1][1], 0, 0, 0);
    acc[0][2] = __builtin_amdgcn_mfma_f32_16x16x32_bf16(cA0, cB2, acc[0][2], 0, 0, 0);
    acc[1][2] = __builtin_amdgcn_mfma_f32_16x16x32_bf16(cA1, cB2, acc[1][2], 0, 0, 0);
    acc[0][3] = __builtin_amdgcn_mfma_f32_16x16x32_bf16(cA0, cB3, acc[0][3], 0, 0, 0);
    acc[1][3] = __builtin_amdgcn_mfma_f32_16x16x32_bf16(cA1, cB3, acc[1][3], 0, 0, 0);
    cA0 = nA0; cA1 = nA1;
    cB0 = nB0; cB1 = nB1; cB2 = nB2; cB3 = nB3;
  }
#pragma unroll
  for (int mt = 0; mt < 2; mt++) {
#pragma unroll
    for (int r = 0; r < 4; r++) {
      int m = mw + mt * 16 + quad * 4 + r;
#pragma unroll
      for (int t = 0; t < 4; t++) {
        int n = n0 + t * 16 + l16;
        outp[(size_t)m * 512 + n] =
            acc[mt][t][r] + bo[n] + bf2f(hbf[(size_t)m * 512 + n]);
      }
    }
  }
}

// ---------------------------------------------------------------------------
// layernorm in place on d_out, one block per row
// ---------------------------------------------------------------------------
__global__ __launch_bounds__(256) void ln_kernel(float* __restrict__ o,
                                                 const float* __restrict__ g,
                                                 const float* __restrict__ bb) {
  int row = blockIdx.x;
  int tid = threadIdx.x;
  float v0 = o[row * 512 + tid];
  float v1 = o[row * 512 + 256 + tid];
  float s = v0 + v1;
  float s2 = v0 * v0 + v1 * v1;
#pragma unroll
  for (int off = 1; off < 64; off <<= 1) {
    s += __shfl_xor(s, off);
    s2 += __shfl_xor(s2, off);
  }
  __shared__ float ps[4], ps2[4];
  int w = tid >> 6;
  if ((tid & 63) == 0) { ps[w] = s; ps2[w] = s2; }
  __syncthreads();
  float S = ps[0] + ps[1] + ps[2] + ps[3];
  float S2 = ps2[0] + ps2[1] + ps2[2] + ps2[3];
  float mu = S * (1.f / 512.f);
  float var = S2 * (1.f / 512.f) - mu * mu;
  float inv = rsqrtf(var + 1e-5f);
  o[row * 512 + tid] = (v0 - mu) * inv * g[tid] + bb[tid];
  o[row * 512 + 256 + tid] = (v1 - mu) * inv * g[tid + 256] + bb[tid + 256];
}

// ---------------------------------------------------------------------------
extern "C" void kernel_launch(void* const* d_in, const int* in_sizes, int n_in,
                              void* d_out, int out_size, void* d_ws,
                              size_t ws_size, hipStream_t stream) {
  const float* x   = (const float*)d_in[0];
  const float* w1  = (const float*)d_in[1];
  const float* b1  = (const float*)d_in[2];
  const float* w2  = (const float*)d_in[3];
  const float* b2  = (const float*)d_in[4];
  const float* w3  = (const float*)d_in[5];
  const float* b3  = (const float*)d_in[6];
  const float* Wq  = (const float*)d_in[7];
  const float* bq  = (const float*)d_in[8];
  const float* Wk  = (const float*)d_in[9];
  const float* bk  = (const float*)d_in[10];
  const float* Wv  = (const float*)d_in[11];
  const float* bv  = (const float*)d_in[12];
  const float* Wkp = (const float*)d_in[13];
  const float* bkp = (const float*)d_in[14];
  const float* Wvp = (const float*)d_in[15];
  const float* bvp = (const float*)d_in[16];
  const float* Wo  = (const float*)d_in[17];
  const float* bo  = (const float*)d_in[18];
  const float* lng = (const float*)d_in[19];
  const float* lnb = (const float*)d_in[20];

  float* p = (float*)d_ws;
  short* Wallbf = (short*)p;  p += 786432;
  float* ball   = p;          p += 2048;
  short* Wobf   = (short*)p;  p += 262144;
  short* Wkpbf  = (short*)p;  p += 4096;
  short* W2bf   = (short*)p;  p += 4096;
  float* cvec   = p;          p += 64;
  short* hbf    = (short*)p;  p += 1048576;
  short* Qh     = (short*)p;  p += 1048576;
  short* Kh     = (short*)p;  p += 1048576;
  short* Vh     = (short*)p;  p += 1048576;
  short* Kph    = (short*)p;  p += 1048576;
  float* Vpp    = p;          p += 2097152;
  float* ctxl   = p;          p += 2097152;
  short* ctxcb  = (short*)p;  p += 1048576;
  float* outF   = (float*)d_out;

  conv_prep_kernel<<<768, 256, 0, stream>>>(
      x, w1, b1, w2, b2, w3, b3, hbf, Wq, Wk, Wv, bq, bk, bv, Wo, Wkp, Wvp,
      bvp, Wallbf, ball, Wobf, Wkpbf, W2bf, cvec);
  {
    dim3 g(32, 24);
    gemm_qkv<<<g, 256, 0, stream>>>(hbf, Wallbf, ball, Qh, Kh, Vh);
  }
  kpvp_local_kernel<<<768, 256, 0, stream>>>(Kh, Vh, Wkpbf, bkp, W2bf, cvec,
                                             Kph, Vpp, Qh, ctxl);
  global_attn<<<256, 512, 0, stream>>>(Qh, Kph, Vpp, ctxl, ctxcb);
  {
    dim3 g(32, 8);
    gemm_wo<<<g, 256, 0, stream>>>(ctxcb, Wobf, bo, hbf, outF);
  }
  ln_kernel<<<4096, 256, 0, stream>>>(outF, lng, lnb);
}

// Round 9
// 239.800 us; speedup vs baseline: 1.2210x; 1.1338x over previous
//
#include <hip/hip_runtime.h>
#include <hip/hip_bf16.h>

#define BB 2
#define SS 2048
#define INC 64
#define HIDN 512
#define NHH 8
#define HDD 64
#define SP 2054   // padded seq rows per batch (3 zero + 2048 + 3 zero)

typedef __attribute__((ext_vector_type(8))) short bf16x8;
typedef __attribute__((ext_vector_type(4))) float f32x4;

__device__ __forceinline__ short f2bf(float f) {
  union { __hip_bfloat16 h; short s; } u;
  u.h = __float2bfloat16(f);
  return u.s;
}
__device__ __forceinline__ float bf2f(short s) {
  return __uint_as_float(((unsigned)(unsigned short)s) << 16);
}

// ---------------------------------------------------------------------------
// prep: all weight conversions + conv GEMM packing.
//  - Wallbf (QKV concat), Wobf, Wkpbf, W2bf/cvec (folded Vp double-proj), ball
//  - xbfp[b][3+s+3][64] bf16: x with 3 zero-pad rows per batch end
//  - Wcbf[512][448] bf16: unified 7-tap conv weights (zero-padded taps)
//  - bcat[512]: concat conv biases
// ---------------------------------------------------------------------------
__global__ __launch_bounds__(256) void prep_kernel(
    const float* __restrict__ x, const float* __restrict__ w1,
    const float* __restrict__ b1, const float* __restrict__ w2,
    const float* __restrict__ b2, const float* __restrict__ w3,
    const float* __restrict__ b3, const float* __restrict__ Wq,
    const float* __restrict__ Wk_, const float* __restrict__ Wv_,
    const float* __restrict__ bq, const float* __restrict__ bk_,
    const float* __restrict__ bv_, const float* __restrict__ Wo,
    const float* __restrict__ Wkp, const float* __restrict__ Wvp,
    const float* __restrict__ bvp, short* __restrict__ Wallbf,
    float* __restrict__ ball, short* __restrict__ Wobf,
    short* __restrict__ Wkpbf, short* __restrict__ W2bf,
    float* __restrict__ cvec, short* __restrict__ xbfp,
    short* __restrict__ Wcbf, float* __restrict__ bcat) {
  int i0 = blockIdx.x * 256 + threadIdx.x;
  int stride = gridDim.x * 256;
  for (int idx = i0; idx < 786432; idx += stride) {
    float v;
    if (idx < 262144)      v = Wq[idx];
    else if (idx < 524288) v = Wk_[idx - 262144];
    else                   v = Wv_[idx - 524288];
    Wallbf[idx] = f2bf(v);
  }
  for (int idx = i0; idx < 262144; idx += stride) Wobf[idx] = f2bf(Wo[idx]);
  // xbfp: padded bf16 copy of x. rows per batch: SP = 3 + 2048 + 3.
  for (int idx = i0; idx < BB * SP * 64; idx += stride) {
    int row = idx >> 6, ci = idx & 63;
    int b = row / SP, pr = row - b * SP;
    int sg = pr - 3;
    float v = (sg >= 0 && sg < SS) ? x[(b * SS + sg) * 64 + ci] : 0.f;
    xbfp[idx] = f2bf(v);
  }
  // Wcbf[c][tap*64+ci]: unified 7-tap weights.
  for (int idx = i0; idx < 512 * 448; idx += stride) {
    int c = idx / 448;
    int rem = idx - c * 448;
    int t = rem >> 6, ci = rem & 63;
    float v = 0.f;
    if (c < 171) {
      int k = t - 2;
      if (k >= 0 && k < 3) v = w1[(c * 64 + ci) * 3 + k];
    } else if (c < 342) {
      int k = t - 1;
      if (k >= 0 && k < 5) v = w2[((c - 171) * 64 + ci) * 5 + k];
    } else {
      v = w3[((c - 342) * 64 + ci) * 7 + t];
    }
    Wcbf[idx] = f2bf(v);
  }
  for (int idx = i0; idx < 4096; idx += stride) {
    Wkpbf[idx] = f2bf(Wkp[idx]);
    int j = idx >> 6, d = idx & 63;
    float s = 0.f;
#pragma unroll 8
    for (int i = 0; i < 64; i++) s += Wvp[j * 64 + i] * Wvp[i * 64 + d];
    W2bf[idx] = f2bf(s);
  }
  if (i0 < 1536) {
    float v;
    if (i0 < 512)       v = bq[i0];
    else if (i0 < 1024) v = bk_[i0 - 512];
    else                v = bv_[i0 - 1024];
    ball[i0] = v;
  }
  if (i0 < 512) {
    float v;
    if (i0 < 171)      v = b1[i0];
    else if (i0 < 342) v = b2[i0 - 171];
    else               v = b3[i0 - 342];
    bcat[i0] = v;
  }
  if (i0 < 64) {
    float s = bvp[i0];
#pragma unroll 8
    for (int i = 0; i < 64; i++) s += bvp[i] * Wvp[i0 * 64 + i];
    cvec[i0] = s;
  }
}

// ---------------------------------------------------------------------------
// conv as MFMA GEMM (v9): h[s,c] = relu(sum_{t,ci} xpad[s+t-3,ci]*Wc[c,t,ci]
// + bcat[c]). Since K-layout=[tap][ci] and xbfp rows are contiguous, the
// im2col A-row is the CONTIGUOUS 448-elem slice at xbfp[(b*SP+s)*64] — plain
// GEMM, M=4096 N=512 K=448. Replaces the scalar-fp32 conv whose per-lane
// weight gathers (64 lines/instr, 655KB set) were the r8 #1 (61-65us,
// VALUBusy 31%, latency-bound).
// ---------------------------------------------------------------------------
__global__ __launch_bounds__(256, 4) void gemm_conv(
    const short* __restrict__ xbfp, const short* __restrict__ Wcbf,
    const float* __restrict__ bcat, short* __restrict__ hbf) {
  int m0 = blockIdx.x * 128;
  int n0 = blockIdx.y * 64;
  int tid = threadIdx.x;
  int wvv = tid >> 6, lane = tid & 63;
  int quad = lane >> 4, l16 = lane & 15;
  int mw = m0 + wvv * 32;
  int r0 = mw + l16, r1 = r0 + 16;
  int b0 = r0 >> 11, s0 = r0 & 2047;
  int b1 = r1 >> 11, s1 = r1 & 2047;
  const short* ap0 = xbfp + (size_t)(b0 * SP + s0) * 64 + quad * 8;
  const short* ap1 = xbfp + (size_t)(b1 * SP + s1) * 64 + quad * 8;
  const short* bp = Wcbf + (size_t)(n0 + l16) * 448 + quad * 8;
  f32x4 acc[2][4] = {};
  bf16x8 cA0 = *(const bf16x8*)ap0;
  bf16x8 cA1 = *(const bf16x8*)ap1;
  bf16x8 cB0 = *(const bf16x8*)(bp + 0 * 16 * 448);
  bf16x8 cB1 = *(const bf16x8*)(bp + 1 * 16 * 448);
  bf16x8 cB2 = *(const bf16x8*)(bp + 2 * 16 * 448);
  bf16x8 cB3 = *(const bf16x8*)(bp + 3 * 16 * 448);
#pragma unroll 2
  for (int ks = 0; ks < 14; ks++) {
    int offn = (ks + 1 < 14 ? ks + 1 : 13) * 32;
    bf16x8 nA0 = *(const bf16x8*)(ap0 + offn);
    bf16x8 nA1 = *(const bf16x8*)(ap1 + offn);
    bf16x8 nB0 = *(const bf16x8*)(bp + 0 * 16 * 448 + offn);
    bf16x8 nB1 = *(const bf16x8*)(bp + 1 * 16 * 448 + offn);
    bf16x8 nB2 = *(const bf16x8*)(bp + 2 * 16 * 448 + offn);
    bf16x8 nB3 = *(const bf16x8*)(bp + 3 * 16 * 448 + offn);
    acc[0][0] = __builtin_amdgcn_mfma_f32_16x16x32_bf16(cA0, cB0, acc[0][0], 0, 0, 0);
    acc[1][0] = __builtin_amdgcn_mfma_f32_16x16x32_bf16(cA1, cB0, acc[1][0], 0, 0, 0);
    acc[0][1] = __builtin_amdgcn_mfma_f32_16x16x32_bf16(cA0, cB1, acc[0][1], 0, 0, 0);
    acc[1][1] = __builtin_amdgcn_mfma_f32_16x16x32_bf16(cA1, cB1, acc[1][1], 0, 0, 0);
    acc[0][2] = __builtin_amdgcn_mfma_f32_16x16x32_bf16(cA0, cB2, acc[0][2], 0, 0, 0);
    acc[1][2] = __builtin_amdgcn_mfma_f32_16x16x32_bf16(cA1, cB2, acc[1][2], 0, 0, 0);
    acc[0][3] = __builtin_amdgcn_mfma_f32_16x16x32_bf16(cA0, cB3, acc[0][3], 0, 0, 0);
    acc[1][3] = __builtin_amdgcn_mfma_f32_16x16x32_bf16(cA1, cB3, acc[1][3], 0, 0, 0);
    cA0 = nA0; cA1 = nA1;
    cB0 = nB0; cB1 = nB1; cB2 = nB2; cB3 = nB3;
  }
#pragma unroll
  for (int mt = 0; mt < 2; mt++) {
#pragma unroll
    for (int r = 0; r < 4; r++) {
      int m = mw + mt * 16 + quad * 4 + r;
#pragma unroll
      for (int t = 0; t < 4; t++) {
        int n = n0 + t * 16 + l16;
        float v = fmaxf(acc[mt][t][r] + bcat[n], 0.f);
        hbf[(size_t)m * 512 + n] = f2bf(v);
      }
    }
  }
}

// ---------------------------------------------------------------------------
// MFMA QKV gemm: 128-row blocks, wave = 32 rows x 64 cols.
// ---------------------------------------------------------------------------
__global__ __launch_bounds__(256, 4) void gemm_qkv(
    const short* __restrict__ Abf, const short* __restrict__ Wbf,
    const float* __restrict__ bias, short* __restrict__ Qh,
    short* __restrict__ Kh, short* __restrict__ Vh) {
  int m0 = blockIdx.x * 128;
  int n0 = blockIdx.y * 64;
  int tid = threadIdx.x;
  int wvv = tid >> 6, lane = tid & 63;
  int quad = lane >> 4, l16 = lane & 15;
  int mw = m0 + wvv * 32;
  const short* ap0 = Abf + (size_t)(mw + l16) * 512 + quad * 8;
  const short* ap1 = ap0 + 16 * 512;
  const short* bp = Wbf + (size_t)(n0 + l16) * 512 + quad * 8;
  f32x4 acc[2][4] = {};
  bf16x8 cA0 = *(const bf16x8*)ap0;
  bf16x8 cA1 = *(const bf16x8*)ap1;
  bf16x8 cB0 = *(const bf16x8*)(bp + 0 * 16 * 512);
  bf16x8 cB1 = *(const bf16x8*)(bp + 1 * 16 * 512);
  bf16x8 cB2 = *(const bf16x8*)(bp + 2 * 16 * 512);
  bf16x8 cB3 = *(const bf16x8*)(bp + 3 * 16 * 512);
#pragma unroll 2
  for (int ks = 0; ks < 16; ks++) {
    int offn = (ks + 1 < 16 ? ks + 1 : 15) * 32;
    bf16x8 nA0 = *(const bf16x8*)(ap0 + offn);
    bf16x8 nA1 = *(const bf16x8*)(ap1 + offn);
    bf16x8 nB0 = *(const bf16x8*)(bp + 0 * 16 * 512 + offn);
    bf16x8 nB1 = *(const bf16x8*)(bp + 1 * 16 * 512 + offn);
    bf16x8 nB2 = *(const bf16x8*)(bp + 2 * 16 * 512 + offn);
    bf16x8 nB3 = *(const bf16x8*)(bp + 3 * 16 * 512 + offn);
    acc[0][0] = __builtin_amdgcn_mfma_f32_16x16x32_bf16(cA0, cB0, acc[0][0], 0, 0, 0);
    acc[1][0] = __builtin_amdgcn_mfma_f32_16x16x32_bf16(cA1, cB0, acc[1][0], 0, 0, 0);
    acc[0][1] = __builtin_amdgcn_mfma_f32_16x16x32_bf16(cA0, cB1, acc[0][1], 0, 0, 0);
    acc[1][1] = __builtin_amdgcn_mfma_f32_16x16x32_bf16(cA1, cB1, acc[1][1], 0, 0, 0);
    acc[0][2] = __builtin_amdgcn_mfma_f32_16x16x32_bf16(cA0, cB2, acc[0][2], 0, 0, 0);
    acc[1][2] = __builtin_amdgcn_mfma_f32_16x16x32_bf16(cA1, cB2, acc[1][2], 0, 0, 0);
    acc[0][3] = __builtin_amdgcn_mfma_f32_16x16x32_bf16(cA0, cB3, acc[0][3], 0, 0, 0);
    acc[1][3] = __builtin_amdgcn_mfma_f32_16x16x32_bf16(cA1, cB3, acc[1][3], 0, 0, 0);
    cA0 = nA0; cA1 = nA1;
    cB0 = nB0; cB1 = nB1; cB2 = nB2; cB3 = nB3;
  }
  int which = n0 >> 9;
  int head = (n0 >> 6) & 7;
  short* dst = which == 0 ? Qh : (which == 1 ? Kh : Vh);
  float scale = which == 0 ? 0.125f : 1.0f;
#pragma unroll
  for (int mt = 0; mt < 2; mt++) {
#pragma unroll
    for (int r = 0; r < 4; r++) {
      int m = mw + mt * 16 + quad * 4 + r;
      int bb = m >> 11, s = m & 2047;
      size_t rowoff = ((size_t)(bb * 8 + head) * 2048 + s) * 64;
#pragma unroll
      for (int t = 0; t < 4; t++) {
        int hd = t * 16 + l16;
        float v = acc[mt][t][r] + bias[n0 + hd];
        dst[rowoff + hd] = f2bf(v * scale);
      }
    }
  }
}

// ---------------------------------------------------------------------------
// kpvp + local_attn fused.
// ---------------------------------------------------------------------------
__global__ __launch_bounds__(256, 4) void kpvp_local_kernel(
    const short* __restrict__ Kh, const short* __restrict__ Vh,
    const short* __restrict__ Wkpbf, const float* __restrict__ bkp,
    const short* __restrict__ W2bf, const float* __restrict__ cvec,
    short* __restrict__ Kph, float* __restrict__ Vpp,
    const short* __restrict__ Qh, float* __restrict__ ctxl) {
  int tid = threadIdx.x;
  __shared__ float Sloc[4][2][16][17];
  __shared__ float wloc[4][16][8];
  if (blockIdx.x < 256) {
    int m0 = blockIdx.x * 128;
    int wvv = tid >> 6, lane = tid & 63;
    int quad = lane >> 4, l16 = lane & 15;
    int mw = m0 + wvv * 32;
    {
      const short* ap0 = Kh + (size_t)(mw + l16) * 64 + quad * 8;
      const short* ap1 = ap0 + 16 * 64;
      const short* bp = Wkpbf + l16 * 64 + quad * 8;
      bf16x8 A00 = *(const bf16x8*)ap0, A01 = *(const bf16x8*)(ap0 + 32);
      bf16x8 A10 = *(const bf16x8*)ap1, A11 = *(const bf16x8*)(ap1 + 32);
      f32x4 acc[2][4] = {};
#pragma unroll
      for (int t = 0; t < 4; t++) {
        bf16x8 B0 = *(const bf16x8*)(bp + t * 16 * 64);
        bf16x8 B1 = *(const bf16x8*)(bp + t * 16 * 64 + 32);
        acc[0][t] = __builtin_amdgcn_mfma_f32_16x16x32_bf16(A00, B0, acc[0][t], 0, 0, 0);
        acc[0][t] = __builtin_amdgcn_mfma_f32_16x16x32_bf16(A01, B1, acc[0][t], 0, 0, 0);
        acc[1][t] = __builtin_amdgcn_mfma_f32_16x16x32_bf16(A10, B0, acc[1][t], 0, 0, 0);
        acc[1][t] = __builtin_amdgcn_mfma_f32_16x16x32_bf16(A11, B1, acc[1][t], 0, 0, 0);
      }
#pragma unroll
      for (int mt = 0; mt < 2; mt++)
#pragma unroll
        for (int r = 0; r < 4; r++) {
          int m = mw + mt * 16 + quad * 4 + r;
#pragma unroll
          for (int t = 0; t < 4; t++) {
            int n = t * 16 + l16;
            Kph[(size_t)m * 64 + n] = f2bf(acc[mt][t][r] + bkp[n]);
          }
        }
    }
    {
      const short* ap0 = Vh + (size_t)(mw + l16) * 64 + quad * 8;
      const short* ap1 = ap0 + 16 * 64;
      const short* bp = W2bf + l16 * 64 + quad * 8;
      bf16x8 A00 = *(const bf16x8*)ap0, A01 = *(const bf16x8*)(ap0 + 32);
      bf16x8 A10 = *(const bf16x8*)ap1, A11 = *(const bf16x8*)(ap1 + 32);
      f32x4 acc[2][4] = {};
#pragma unroll
      for (int t = 0; t < 4; t++) {
        bf16x8 B0 = *(const bf16x8*)(bp + t * 16 * 64);
        bf16x8 B1 = *(const bf16x8*)(bp + t * 16 * 64 + 32);
        acc[0][t] = __builtin_amdgcn_mfma_f32_16x16x32_bf16(A00, B0, acc[0][t], 0, 0, 0);
        acc[0][t] = __builtin_amdgcn_mfma_f32_16x16x32_bf16(A01, B1, acc[0][t], 0, 0, 0);
        acc[1][t] = __builtin_amdgcn_mfma_f32_16x16x32_bf16(A10, B0, acc[1][t], 0, 0, 0);
        acc[1][t] = __builtin_amdgcn_mfma_f32_16x16x32_bf16(A11, B1, acc[1][t], 0, 0, 0);
      }
#pragma unroll
      for (int mt = 0; mt < 2; mt++)
#pragma unroll
        for (int r = 0; r < 4; r++) {
          int m = mw + mt * 16 + quad * 4 + r;
#pragma unroll
          for (int t = 0; t < 4; t++) {
            int n = t * 16 + l16;
            Vpp[(size_t)m * 64 + n] = acc[mt][t][r] + cvec[n];
          }
        }
    }
    return;
  }
  // ---- local windowed attention ----
  int wv = tid >> 6;
  int tile = (blockIdx.x - 256) * 4 + wv;   // 0..2047
  int bh = tile >> 7;
  int q0 = (tile & 127) * 16;
  int lane = tid & 63;
  int quad = lane >> 4, l16 = lane & 15;

  const short* qbase = Qh + (size_t)(bh * 2048 + q0 + l16) * 64 + quad * 8;
  bf16x8 a0 = *(const bf16x8*)qbase;
  bf16x8 a1 = *(const bf16x8*)(qbase + 32);

  int k0a = min(max(q0 - 2 + l16, 0), 2047);
  int k1a = min(q0 + 6 + l16, 2047);
  const short* kb0 = Kh + (size_t)(bh * 2048 + k0a) * 64 + quad * 8;
  const short* kb1 = Kh + (size_t)(bh * 2048 + k1a) * 64 + quad * 8;
  bf16x8 B00 = *(const bf16x8*)kb0;
  bf16x8 B01 = *(const bf16x8*)(kb0 + 32);
  bf16x8 B10 = *(const bf16x8*)kb1;
  bf16x8 B11 = *(const bf16x8*)(kb1 + 32);
  f32x4 C0 = {0.f, 0.f, 0.f, 0.f};
  f32x4 C1 = {0.f, 0.f, 0.f, 0.f};
  C0 = __builtin_amdgcn_mfma_f32_16x16x32_bf16(a0, B00, C0, 0, 0, 0);
  C0 = __builtin_amdgcn_mfma_f32_16x16x32_bf16(a1, B01, C0, 0, 0, 0);
  C1 = __builtin_amdgcn_mfma_f32_16x16x32_bf16(a0, B10, C1, 0, 0, 0);
  C1 = __builtin_amdgcn_mfma_f32_16x16x32_bf16(a1, B11, C1, 0, 0, 0);
#pragma unroll
  for (int r = 0; r < 4; r++) {
    Sloc[wv][0][quad * 4 + r][l16] = C0[r];
    Sloc[wv][1][quad * 4 + r][l16] = C1[r];
  }
  __builtin_amdgcn_wave_barrier();
  if (lane < 16) {
    int q = lane;
    float sc[5];
    bool ok[5];
#pragma unroll
    for (int j = 0; j < 5; j++) {
      int offq = q + j - 2;
      int sg = q0 + offq;
      ok[j] = (sg >= 0 && sg < SS);
      int t = offq <= 13 ? 0 : 1;
      int col = t ? offq - 6 : offq + 2;
      sc[j] = ok[j] ? Sloc[wv][t][q][col] : -3.0e38f;
    }
    float m = -3.0e38f;
#pragma unroll
    for (int j = 0; j < 5; j++) m = fmaxf(m, sc[j]);
    float e[5], l = 0.f;
#pragma unroll
    for (int j = 0; j < 5; j++) {
      e[j] = ok[j] ? __expf(sc[j] - m) : 0.f;
      l += e[j];
    }
    float inv = 1.f / l;
#pragma unroll
    for (int j = 0; j < 5; j++) wloc[wv][q][j] = e[j] * inv;
  }
  __builtin_amdgcn_wave_barrier();
  {
    int q = lane >> 2, jb = (lane & 3) * 16;
    int s = q0 + q;
    float acc[16] = {};
#pragma unroll
    for (int j = 0; j < 5; j++) {
      int sg = s + j - 2;
      if (sg >= 0 && sg < SS) {
        float w = wloc[wv][q][j];
        const short* vr = Vh + (size_t)(bh * 2048 + sg) * 64 + jb;
#pragma unroll
        for (int u = 0; u < 16; u += 4) {
          short4 v4 = *(const short4*)(vr + u);
          acc[u + 0] += w * bf2f(v4.x);
          acc[u + 1] += w * bf2f(v4.y);
          acc[u + 2] += w * bf2f(v4.z);
          acc[u + 3] += w * bf2f(v4.w);
        }
      }
    }
    float* orow = ctxl + (size_t)(bh * 2048 + s) * 64 + jb;
#pragma unroll
    for (int u = 0; u < 16; u += 4)
      *(float4*)(orow + u) =
          make_float4(acc[u], acc[u + 1], acc[u + 2], acc[u + 3]);
  }
}

// ---------------------------------------------------------------------------
// global sparse attention — v8 (kept): LDS-staged K panel, one block per CU.
// ---------------------------------------------------------------------------
__global__ __launch_bounds__(512, 1) void global_attn(
    const short* __restrict__ Qh, const short* __restrict__ Kph,
    const float* __restrict__ Vpp, const float* __restrict__ ctxl,
    short* __restrict__ ctxcb) {
  int tid = threadIdx.x;
  int wv = tid >> 6;
  int lane = tid & 63;
  int quad = lane >> 4, l16 = lane & 15;
  int p = blockIdx.x;                       // 0..255
  int bh = (p & 7) * 2 + ((p >> 3) & 1);    // XCD-affine
  int seg = p >> 4;                         // 0..15
  int tile = seg * 8 + wv;                  // tile within bh: 0..127
  int q0 = tile * 16;

  __shared__ short Ks[2][128][64];          // 32 KB, col-swizzled
  __shared__ float twl[8][16][17];
  __shared__ int   txl[8][16][17];

  const short* qbase = Qh + (size_t)(bh * 2048 + q0 + l16) * 64 + quad * 8;
  bf16x8 a0 = *(const bf16x8*)qbase;
  bf16x8 a1 = *(const bf16x8*)(qbase + 32);

  const short* kpanel = Kph + (size_t)bh * (2048 * 64);

  unsigned er[4][8];
#pragma unroll
  for (int a = 0; a < 4; a++)
#pragma unroll
    for (int j = 0; j < 8; j++) er[a][j] = 0u;

  auto insert8 = [&](unsigned (&e)[8], unsigned cand) {
    unsigned n0, n1, n2, n3, n4, n5, n6, n7;
    asm("v_max_u32 %0, %1, %2" : "=v"(n0) : "v"(e[0]), "v"(cand));
    asm("v_med3_u32 %0, %1, %2, %3" : "=v"(n1) : "v"(e[0]), "v"(e[1]), "v"(cand));
    asm("v_med3_u32 %0, %1, %2, %3" : "=v"(n2) : "v"(e[1]), "v"(e[2]), "v"(cand));
    asm("v_med3_u32 %0, %1, %2, %3" : "=v"(n3) : "v"(e[2]), "v"(e[3]), "v"(cand));
    asm("v_med3_u32 %0, %1, %2, %3" : "=v"(n4) : "v"(e[3]), "v"(e[4]), "v"(cand));
    asm("v_med3_u32 %0, %1, %2, %3" : "=v"(n5) : "v"(e[4]), "v"(e[5]), "v"(cand));
    asm("v_med3_u32 %0, %1, %2, %3" : "=v"(n6) : "v"(e[5]), "v"(e[6]), "v"(cand));
    asm("v_med3_u32 %0, %1, %2, %3" : "=v"(n7) : "v"(e[6]), "v"(e[7]), "v"(cand));
    e[0] = n0; e[1] = n1; e[2] = n2; e[3] = n3;
    e[4] = n4; e[5] = n5; e[6] = n6; e[7] = n7;
  };
  auto mkcand = [&](float s, int idxr) -> unsigned {
    unsigned u = __float_as_uint(s);
    u ^= ((unsigned)((int)u >> 31)) | 0x80000000u;
    return (u & 0xFFFFF800u) | (unsigned)idxr;
  };

  int skey = tid >> 2;
  int scol = (tid & 3) * 16;
  int ssw = (skey & 7) << 3;
  const short* gsrc = kpanel + (size_t)tid * 16;

  bf16x8 c0 = *(const bf16x8*)gsrc;
  bf16x8 c1 = *(const bf16x8*)(gsrc + 8);
  {
    short* dst = &Ks[0][skey][0];
    *(bf16x8*)(dst + (scol ^ ssw)) = c0;
    *(bf16x8*)(dst + ((scol + 8) ^ ssw)) = c1;
  }
  __syncthreads();

  int rsw = ((l16 & 7) << 3);
#pragma unroll 1
  for (int ck = 0; ck < 16; ck++) {
    int cb = ck & 1, nb = cb ^ 1;
    bf16x8 p0, p1;
    if (ck < 15) {
      const short* ng = kpanel + (size_t)(ck + 1) * 8192 + tid * 16;
      p0 = *(const bf16x8*)ng;
      p1 = *(const bf16x8*)(ng + 8);
    }
#pragma unroll
    for (int gg = 0; gg < 4; gg++) {
      int k0 = gg * 32 + l16;
      int k1 = k0 + 16;
      const short* s0 = &Ks[cb][k0][0];
      const short* s1 = &Ks[cb][k1][0];
      bf16x8 B00 = *(const bf16x8*)(s0 + ((quad * 8) ^ rsw));
      bf16x8 B01 = *(const bf16x8*)(s0 + ((quad * 8 + 32) ^ rsw));
      bf16x8 B10 = *(const bf16x8*)(s1 + ((quad * 8) ^ rsw));
      bf16x8 B11 = *(const bf16x8*)(s1 + ((quad * 8 + 32) ^ rsw));
      f32x4 C0 = {0.f, 0.f, 0.f, 0.f};
      f32x4 C1 = {0.f, 0.f, 0.f, 0.f};
      C0 = __builtin_amdgcn_mfma_f32_16x16x32_bf16(a0, B00, C0, 0, 0, 0);
      C0 = __builtin_amdgcn_mfma_f32_16x16x32_bf16(a1, B01, C0, 0, 0, 0);
      C1 = __builtin_amdgcn_mfma_f32_16x16x32_bf16(a0, B10, C1, 0, 0, 0);
      C1 = __builtin_amdgcn_mfma_f32_16x16x32_bf16(a1, B11, C1, 0, 0, 0);
      int idxr0 = 2047 - (ck * 128 + gg * 32) - l16;
      int idxr1 = idxr0 - 16;
      insert8(er[0], mkcand(C0[0], idxr0));
      insert8(er[1], mkcand(C0[1], idxr0));
      insert8(er[2], mkcand(C0[2], idxr0));
      insert8(er[3], mkcand(C0[3], idxr0));
      insert8(er[0], mkcand(C1[0], idxr1));
      insert8(er[1], mkcand(C1[1], idxr1));
      insert8(er[2], mkcand(C1[2], idxr1));
      insert8(er[3], mkcand(C1[3], idxr1));
    }
    __syncthreads();
    if (ck < 15) {
      short* dst = &Ks[nb][skey][0];
      *(bf16x8*)(dst + (scol ^ ssw)) = p0;
      *(bf16x8*)(dst + ((scol + 8) ^ ssw)) = p1;
      __syncthreads();
    }
  }

  {
    float mval[4] = {0.f, 0.f, 0.f, 0.f};
    float lsum[4] = {0.f, 0.f, 0.f, 0.f};
    float myev[4] = {0.f, 0.f, 0.f, 0.f};
    int myki[4] = {0, 0, 0, 0};
#pragma unroll
    for (int t = 0; t < 16; t++) {
#pragma unroll
      for (int a = 0; a < 4; a++) {
        unsigned w = er[a][0];
#pragma unroll
        for (int mm = 1; mm <= 8; mm <<= 1) {
          unsigned o = (unsigned)__shfl_xor((int)w, mm);
          w = w > o ? w : o;
        }
        bool pop = (er[a][0] == w);
#pragma unroll
        for (int j = 0; j < 7; j++) er[a][j] = pop ? er[a][j + 1] : er[a][j];
        er[a][7] = pop ? 0u : er[a][7];
        unsigned wb = w & 0xFFFFF800u;
        unsigned uu = (w & 0x80000000u) ? (wb ^ 0x80000000u) : ~wb;
        float sv = (w == 0u) ? -1.0e30f : __uint_as_float(uu);
        if (t == 0) mval[a] = sv;
        float ex = __expf(sv - mval[a]);
        lsum[a] += ex;
        if (l16 == t) { myev[a] = ex; myki[a] = 2047 - (int)(w & 0x7FFu); }
      }
    }
#pragma unroll
    for (int a = 0; a < 4; a++) {
      twl[wv][quad * 4 + a][l16] = myev[a] / lsum[a];
      txl[wv][quad * 4 + a][l16] = myki[a];
    }
  }
  __builtin_amdgcn_wave_barrier();

  {
    int q = lane >> 2, d0 = (lane & 3) * 16;
    int b = bh >> 3, hh = bh & 7;
    const float* vball = Vpp + (size_t)bh * (2048 * 64) + d0;
    float acc[16];
#pragma unroll
    for (int u = 0; u < 16; u++) acc[u] = 0.f;
#pragma unroll 4
    for (int j = 0; j < 16; j++) {
      float w = twl[wv][q][j];
      const float* vr = vball + (size_t)txl[wv][q][j] * 64;
#pragma unroll
      for (int u = 0; u < 16; u += 4) {
        float4 v = *(const float4*)(vr + u);
        acc[u + 0] += w * v.x;
        acc[u + 1] += w * v.y;
        acc[u + 2] += w * v.z;
        acc[u + 3] += w * v.w;
      }
    }
    int s = q0 + q;
    const float* lrow = ctxl + (size_t)(bh * 2048 + s) * 64 + d0;
    short* orow = ctxcb + (size_t)(b * 2048 + s) * 512 + hh * 64 + d0;
#pragma unroll
    for (int u = 0; u < 16; u += 4) {
      float4 lv = *(const float4*)(lrow + u);
      short4 o;
      o.x = f2bf(0.5f * (lv.x + acc[u + 0]));
      o.y = f2bf(0.5f * (lv.y + acc[u + 1]));
      o.z = f2bf(0.5f * (lv.z + acc[u + 2]));
      o.w = f2bf(0.5f * (lv.w + acc[u + 3]));
      *(short4*)(orow + u) = o;
    }
  }
}

// ---------------------------------------------------------------------------
// MFMA Wo gemm: 128-row blocks, wave = 32 rows. Residual from bf16 hbf.
// ---------------------------------------------------------------------------
__global__ __launch_bounds__(256, 4) void gemm_wo(
    const short* __restrict__ Abf, const short* __restrict__ Wbf,
    const float* __restrict__ bo, const short* __restrict__ hbf,
    float* __restrict__ outp) {
  int m0 = blockIdx.x * 128;
  int n0 = blockIdx.y * 64;
  int tid = threadIdx.x;
  int wvv = tid >> 6, lane = tid & 63;
  int quad = lane >> 4, l16 = lane & 15;
  int mw = m0 + wvv * 32;
  const short* ap0 = Abf + (size_t)(mw + l16) * 512 + quad * 8;
  const short* ap1 = ap0 + 16 * 512;
  const short* bp = Wbf + (size_t)(n0 + l16) * 512 + quad * 8;
  f32x4 acc[2][4] = {};
  bf16x8 cA0 = *(const bf16x8*)ap0;
  bf16x8 cA1 = *(const bf16x8*)ap1;
  bf16x8 cB0 = *(const bf16x8*)(bp + 0 * 16 * 512);
  bf16x8 cB1 = *(const bf16x8*)(bp + 1 * 16 * 512);
  bf16x8 cB2 = *(const bf16x8*)(bp + 2 * 16 * 512);
  bf16x8 cB3 = *(const bf16x8*)(bp + 3 * 16 * 512);
#pragma unroll 2
  for (int ks = 0; ks < 16; ks++) {
    int offn = (ks + 1 < 16 ? ks + 1 : 15) * 32;
    bf16x8 nA0 = *(const bf16x8*)(ap0 + offn);
    bf16x8 nA1 = *(const bf16x8*)(ap1 + offn);
    bf16x8 nB0 = *(const bf16x8*)(bp + 0 * 16 * 512 + offn);
    bf16x8 nB1 = *(const bf16x8*)(bp + 1 * 16 * 512 + offn);
    bf16x8 nB2 = *(const bf16x8*)(bp + 2 * 16 * 512 + offn);
    bf16x8 nB3 = *(const bf16x8*)(bp + 3 * 16 * 512 + offn);
    acc[0][0] = __builtin_amdgcn_mfma_f32_16x16x32_bf16(cA0, cB0, acc[0][0], 0, 0, 0);
    acc[1][0] = __builtin_amdgcn_mfma_f32_16x16x32_bf16(cA1, cB0, acc[1][0], 0, 0, 0);
    acc[0][1] = __builtin_amdgcn_mfma_f32_16x16x32_bf16(cA0, cB1, acc[0][1], 0, 0, 0);
    acc[1][1] = __builtin_amdgcn_mfma_f32_16x16x32_bf16(cA1, cB1, acc[1][1], 0, 0, 0);
    acc[0][2] = __builtin_amdgcn_mfma_f32_16x16x32_bf16(cA0, cB2, acc[0][2], 0, 0, 0);
    acc[1][2] = __builtin_amdgcn_mfma_f32_16x16x32_bf16(cA1, cB2, acc[1][2], 0, 0, 0);
    acc[0][3] = __builtin_amdgcn_mfma_f32_16x16x32_bf16(cA0, cB3, acc[0][3], 0, 0, 0);
    acc[1][3] = __builtin_amdgcn_mfma_f32_16x16x32_bf16(cA1, cB3, acc[1][3], 0, 0, 0);
    cA0 = nA0; cA1 = nA1;
    cB0 = nB0; cB1 = nB1; cB2 = nB2; cB3 = nB3;
  }
#pragma unroll
  for (int mt = 0; mt < 2; mt++) {
#pragma unroll
    for (int r = 0; r < 4; r++) {
      int m = mw + mt * 16 + quad * 4 + r;
#pragma unroll
      for (int t = 0; t < 4; t++) {
        int n = n0 + t * 16 + l16;
        outp[(size_t)m * 512 + n] =
            acc[mt][t][r] + bo[n] + bf2f(hbf[(size_t)m * 512 + n]);
      }
    }
  }
}

// ---------------------------------------------------------------------------
// layernorm in place on d_out, one block per row
// ---------------------------------------------------------------------------
__global__ __launch_bounds__(256) void ln_kernel(float* __restrict__ o,
                                                 const float* __restrict__ g,
                                                 const float* __restrict__ bb) {
  int row = blockIdx.x;
  int tid = threadIdx.x;
  float v0 = o[row * 512 + tid];
  float v1 = o[row * 512 + 256 + tid];
  float s = v0 + v1;
  float s2 = v0 * v0 + v1 * v1;
#pragma unroll
  for (int off = 1; off < 64; off <<= 1) {
    s += __shfl_xor(s, off);
    s2 += __shfl_xor(s2, off);
  }
  __shared__ float ps[4], ps2[4];
  int w = tid >> 6;
  if ((tid & 63) == 0) { ps[w] = s; ps2[w] = s2; }
  __syncthreads();
  float S = ps[0] + ps[1] + ps[2] + ps[3];
  float S2 = ps2[0] + ps2[1] + ps2[2] + ps2[3];
  float mu = S * (1.f / 512.f);
  float var = S2 * (1.f / 512.f) - mu * mu;
  float inv = rsqrtf(var + 1e-5f);
  o[row * 512 + tid] = (v0 - mu) * inv * g[tid] + bb[tid];
  o[row * 512 + 256 + tid] = (v1 - mu) * inv * g[tid + 256] + bb[tid + 256];
}

// ---------------------------------------------------------------------------
extern "C" void kernel_launch(void* const* d_in, const int* in_sizes, int n_in,
                              void* d_out, int out_size, void* d_ws,
                              size_t ws_size, hipStream_t stream) {
  const float* x   = (const float*)d_in[0];
  const float* w1  = (const float*)d_in[1];
  const float* b1  = (const float*)d_in[2];
  const float* w2  = (const float*)d_in[3];
  const float* b2  = (const float*)d_in[4];
  const float* w3  = (const float*)d_in[5];
  const float* b3  = (const float*)d_in[6];
  const float* Wq  = (const float*)d_in[7];
  const float* bq  = (const float*)d_in[8];
  const float* Wk  = (const float*)d_in[9];
  const float* bk  = (const float*)d_in[10];
  const float* Wv  = (const float*)d_in[11];
  const float* bv  = (const float*)d_in[12];
  const float* Wkp = (const float*)d_in[13];
  const float* bkp = (const float*)d_in[14];
  const float* Wvp = (const float*)d_in[15];
  const float* bvp = (const float*)d_in[16];
  const float* Wo  = (const float*)d_in[17];
  const float* bo  = (const float*)d_in[18];
  const float* lng = (const float*)d_in[19];
  const float* lnb = (const float*)d_in[20];

  float* p = (float*)d_ws;
  short* Wallbf = (short*)p;  p += 786432;
  float* ball   = p;          p += 2048;
  short* Wobf   = (short*)p;  p += 262144;
  short* Wkpbf  = (short*)p;  p += 4096;
  short* W2bf   = (short*)p;  p += 4096;
  float* cvec   = p;          p += 64;
  short* xbfp   = (short*)p;  p += 262912;   // BB*SP*64 shorts (over-alloc)
  short* Wcbf   = (short*)p;  p += 229376;   // 512*448 shorts (over-alloc)
  float* bcat   = p;          p += 512;
  short* hbf    = (short*)p;  p += 1048576;
  short* Qh     = (short*)p;  p += 1048576;
  short* Kh     = (short*)p;  p += 1048576;
  short* Vh     = (short*)p;  p += 1048576;
  short* Kph    = (short*)p;  p += 1048576;
  float* Vpp    = p;          p += 2097152;
  float* ctxl   = p;          p += 2097152;
  short* ctxcb  = (short*)p;  p += 1048576;
  float* outF   = (float*)d_out;

  prep_kernel<<<512, 256, 0, stream>>>(x, w1, b1, w2, b2, w3, b3, Wq, Wk, Wv,
                                       bq, bk, bv, Wo, Wkp, Wvp, bvp, Wallbf,
                                       ball, Wobf, Wkpbf, W2bf, cvec, xbfp,
                                       Wcbf, bcat);
  {
    dim3 g(32, 8);
    gemm_conv<<<g, 256, 0, stream>>>(xbfp, Wcbf, bcat, hbf);
  }
  {
    dim3 g(32, 24);
    gemm_qkv<<<g, 256, 0, stream>>>(hbf, Wallbf, ball, Qh, Kh, Vh);
  }
  kpvp_local_kernel<<<768, 256, 0, stream>>>(Kh, Vh, Wkpbf, bkp, W2bf, cvec,
                                             Kph, Vpp, Qh, ctxl);
  global_attn<<<256, 512, 0, stream>>>(Qh, Kph, Vpp, ctxl, ctxcb);
  {
    dim3 g(32, 8);
    gemm_wo<<<g, 256, 0, stream>>>(ctxcb, Wobf, bo, hbf, outF);
  }
  ln_kernel<<<4096, 256, 0, stream>>>(outF, lng, lnb);
}

// Round 10
// 238.520 us; speedup vs baseline: 1.2275x; 1.0054x over previous
//
#include <hip/hip_runtime.h>
#include <hip/hip_bf16.h>

#define BB 2
#define SS 2048
#define INC 64
#define HIDN 512
#define NHH 8
#define HDD 64
#define SP 2054   // padded seq rows per batch (3 zero + 2048 + 3 zero)

typedef __attribute__((ext_vector_type(8))) short bf16x8;
typedef __attribute__((ext_vector_type(4))) float f32x4;

__device__ __forceinline__ short f2bf(float f) {
  union { __hip_bfloat16 h; short s; } u;
  u.h = __float2bfloat16(f);
  return u.s;
}
__device__ __forceinline__ float bf2f(short s) {
  return __uint_as_float(((unsigned)(unsigned short)s) << 16);
}

// ---------------------------------------------------------------------------
// prep: all weight conversions + conv GEMM packing.
// ---------------------------------------------------------------------------
__global__ __launch_bounds__(256) void prep_kernel(
    const float* __restrict__ x, const float* __restrict__ w1,
    const float* __restrict__ b1, const float* __restrict__ w2,
    const float* __restrict__ b2, const float* __restrict__ w3,
    const float* __restrict__ b3, const float* __restrict__ Wq,
    const float* __restrict__ Wk_, const float* __restrict__ Wv_,
    const float* __restrict__ bq, const float* __restrict__ bk_,
    const float* __restrict__ bv_, const float* __restrict__ Wo,
    const float* __restrict__ Wkp, const float* __restrict__ Wvp,
    const float* __restrict__ bvp, short* __restrict__ Wallbf,
    float* __restrict__ ball, short* __restrict__ Wobf,
    short* __restrict__ Wkpbf, short* __restrict__ W2bf,
    float* __restrict__ cvec, short* __restrict__ xbfp,
    short* __restrict__ Wcbf, float* __restrict__ bcat) {
  int i0 = blockIdx.x * 256 + threadIdx.x;
  int stride = gridDim.x * 256;
  for (int idx = i0; idx < 786432; idx += stride) {
    float v;
    if (idx < 262144)      v = Wq[idx];
    else if (idx < 524288) v = Wk_[idx - 262144];
    else                   v = Wv_[idx - 524288];
    Wallbf[idx] = f2bf(v);
  }
  for (int idx = i0; idx < 262144; idx += stride) Wobf[idx] = f2bf(Wo[idx]);
  for (int idx = i0; idx < BB * SP * 64; idx += stride) {
    int row = idx >> 6, ci = idx & 63;
    int b = row / SP, pr = row - b * SP;
    int sg = pr - 3;
    float v = (sg >= 0 && sg < SS) ? x[(b * SS + sg) * 64 + ci] : 0.f;
    xbfp[idx] = f2bf(v);
  }
  for (int idx = i0; idx < 512 * 448; idx += stride) {
    int c = idx / 448;
    int rem = idx - c * 448;
    int t = rem >> 6, ci = rem & 63;
    float v = 0.f;
    if (c < 171) {
      int k = t - 2;
      if (k >= 0 && k < 3) v = w1[(c * 64 + ci) * 3 + k];
    } else if (c < 342) {
      int k = t - 1;
      if (k >= 0 && k < 5) v = w2[((c - 171) * 64 + ci) * 5 + k];
    } else {
      v = w3[((c - 342) * 64 + ci) * 7 + t];
    }
    Wcbf[idx] = f2bf(v);
  }
  for (int idx = i0; idx < 4096; idx += stride) {
    Wkpbf[idx] = f2bf(Wkp[idx]);
    int j = idx >> 6, d = idx & 63;
    float s = 0.f;
#pragma unroll 8
    for (int i = 0; i < 64; i++) s += Wvp[j * 64 + i] * Wvp[i * 64 + d];
    W2bf[idx] = f2bf(s);
  }
  if (i0 < 1536) {
    float v;
    if (i0 < 512)       v = bq[i0];
    else if (i0 < 1024) v = bk_[i0 - 512];
    else                v = bv_[i0 - 1024];
    ball[i0] = v;
  }
  if (i0 < 512) {
    float v;
    if (i0 < 171)      v = b1[i0];
    else if (i0 < 342) v = b2[i0 - 171];
    else               v = b3[i0 - 342];
    bcat[i0] = v;
  }
  if (i0 < 64) {
    float s = bvp[i0];
#pragma unroll 8
    for (int i = 0; i < 64; i++) s += bvp[i] * Wvp[i0 * 64 + i];
    cvec[i0] = s;
  }
}

// ---------------------------------------------------------------------------
// conv as MFMA GEMM: M=4096 N=512 K=448, contiguous im2col rows in xbfp.
// ---------------------------------------------------------------------------
__global__ __launch_bounds__(256, 4) void gemm_conv(
    const short* __restrict__ xbfp, const short* __restrict__ Wcbf,
    const float* __restrict__ bcat, short* __restrict__ hbf) {
  int m0 = blockIdx.x * 128;
  int n0 = blockIdx.y * 64;
  int tid = threadIdx.x;
  int wvv = tid >> 6, lane = tid & 63;
  int quad = lane >> 4, l16 = lane & 15;
  int mw = m0 + wvv * 32;
  int r0 = mw + l16, r1 = r0 + 16;
  int b0 = r0 >> 11, s0 = r0 & 2047;
  int b1 = r1 >> 11, s1 = r1 & 2047;
  const short* ap0 = xbfp + (size_t)(b0 * SP + s0) * 64 + quad * 8;
  const short* ap1 = xbfp + (size_t)(b1 * SP + s1) * 64 + quad * 8;
  const short* bp = Wcbf + (size_t)(n0 + l16) * 448 + quad * 8;
  f32x4 acc[2][4] = {};
  bf16x8 cA0 = *(const bf16x8*)ap0;
  bf16x8 cA1 = *(const bf16x8*)ap1;
  bf16x8 cB0 = *(const bf16x8*)(bp + 0 * 16 * 448);
  bf16x8 cB1 = *(const bf16x8*)(bp + 1 * 16 * 448);
  bf16x8 cB2 = *(const bf16x8*)(bp + 2 * 16 * 448);
  bf16x8 cB3 = *(const bf16x8*)(bp + 3 * 16 * 448);
#pragma unroll 2
  for (int ks = 0; ks < 14; ks++) {
    int offn = (ks + 1 < 14 ? ks + 1 : 13) * 32;
    bf16x8 nA0 = *(const bf16x8*)(ap0 + offn);
    bf16x8 nA1 = *(const bf16x8*)(ap1 + offn);
    bf16x8 nB0 = *(const bf16x8*)(bp + 0 * 16 * 448 + offn);
    bf16x8 nB1 = *(const bf16x8*)(bp + 1 * 16 * 448 + offn);
    bf16x8 nB2 = *(const bf16x8*)(bp + 2 * 16 * 448 + offn);
    bf16x8 nB3 = *(const bf16x8*)(bp + 3 * 16 * 448 + offn);
    acc[0][0] = __builtin_amdgcn_mfma_f32_16x16x32_bf16(cA0, cB0, acc[0][0], 0, 0, 0);
    acc[1][0] = __builtin_amdgcn_mfma_f32_16x16x32_bf16(cA1, cB0, acc[1][0], 0, 0, 0);
    acc[0][1] = __builtin_amdgcn_mfma_f32_16x16x32_bf16(cA0, cB1, acc[0][1], 0, 0, 0);
    acc[1][1] = __builtin_amdgcn_mfma_f32_16x16x32_bf16(cA1, cB1, acc[1][1], 0, 0, 0);
    acc[0][2] = __builtin_amdgcn_mfma_f32_16x16x32_bf16(cA0, cB2, acc[0][2], 0, 0, 0);
    acc[1][2] = __builtin_amdgcn_mfma_f32_16x16x32_bf16(cA1, cB2, acc[1][2], 0, 0, 0);
    acc[0][3] = __builtin_amdgcn_mfma_f32_16x16x32_bf16(cA0, cB3, acc[0][3], 0, 0, 0);
    acc[1][3] = __builtin_amdgcn_mfma_f32_16x16x32_bf16(cA1, cB3, acc[1][3], 0, 0, 0);
    cA0 = nA0; cA1 = nA1;
    cB0 = nB0; cB1 = nB1; cB2 = nB2; cB3 = nB3;
  }
#pragma unroll
  for (int mt = 0; mt < 2; mt++) {
#pragma unroll
    for (int r = 0; r < 4; r++) {
      int m = mw + mt * 16 + quad * 4 + r;
#pragma unroll
      for (int t = 0; t < 4; t++) {
        int n = n0 + t * 16 + l16;
        float v = fmaxf(acc[mt][t][r] + bcat[n], 0.f);
        hbf[(size_t)m * 512 + n] = f2bf(v);
      }
    }
  }
}

// ---------------------------------------------------------------------------
// MFMA QKV gemm: 128-row blocks, wave = 32 rows x 64 cols.
// ---------------------------------------------------------------------------
__global__ __launch_bounds__(256, 4) void gemm_qkv(
    const short* __restrict__ Abf, const short* __restrict__ Wbf,
    const float* __restrict__ bias, short* __restrict__ Qh,
    short* __restrict__ Kh, short* __restrict__ Vh) {
  int m0 = blockIdx.x * 128;
  int n0 = blockIdx.y * 64;
  int tid = threadIdx.x;
  int wvv = tid >> 6, lane = tid & 63;
  int quad = lane >> 4, l16 = lane & 15;
  int mw = m0 + wvv * 32;
  const short* ap0 = Abf + (size_t)(mw + l16) * 512 + quad * 8;
  const short* ap1 = ap0 + 16 * 512;
  const short* bp = Wbf + (size_t)(n0 + l16) * 512 + quad * 8;
  f32x4 acc[2][4] = {};
  bf16x8 cA0 = *(const bf16x8*)ap0;
  bf16x8 cA1 = *(const bf16x8*)ap1;
  bf16x8 cB0 = *(const bf16x8*)(bp + 0 * 16 * 512);
  bf16x8 cB1 = *(const bf16x8*)(bp + 1 * 16 * 512);
  bf16x8 cB2 = *(const bf16x8*)(bp + 2 * 16 * 512);
  bf16x8 cB3 = *(const bf16x8*)(bp + 3 * 16 * 512);
#pragma unroll 2
  for (int ks = 0; ks < 16; ks++) {
    int offn = (ks + 1 < 16 ? ks + 1 : 15) * 32;
    bf16x8 nA0 = *(const bf16x8*)(ap0 + offn);
    bf16x8 nA1 = *(const bf16x8*)(ap1 + offn);
    bf16x8 nB0 = *(const bf16x8*)(bp + 0 * 16 * 512 + offn);
    bf16x8 nB1 = *(const bf16x8*)(bp + 1 * 16 * 512 + offn);
    bf16x8 nB2 = *(const bf16x8*)(bp + 2 * 16 * 512 + offn);
    bf16x8 nB3 = *(const bf16x8*)(bp + 3 * 16 * 512 + offn);
    acc[0][0] = __builtin_amdgcn_mfma_f32_16x16x32_bf16(cA0, cB0, acc[0][0], 0, 0, 0);
    acc[1][0] = __builtin_amdgcn_mfma_f32_16x16x32_bf16(cA1, cB0, acc[1][0], 0, 0, 0);
    acc[0][1] = __builtin_amdgcn_mfma_f32_16x16x32_bf16(cA0, cB1, acc[0][1], 0, 0, 0);
    acc[1][1] = __builtin_amdgcn_mfma_f32_16x16x32_bf16(cA1, cB1, acc[1][1], 0, 0, 0);
    acc[0][2] = __builtin_amdgcn_mfma_f32_16x16x32_bf16(cA0, cB2, acc[0][2], 0, 0, 0);
    acc[1][2] = __builtin_amdgcn_mfma_f32_16x16x32_bf16(cA1, cB2, acc[1][2], 0, 0, 0);
    acc[0][3] = __builtin_amdgcn_mfma_f32_16x16x32_bf16(cA0, cB3, acc[0][3], 0, 0, 0);
    acc[1][3] = __builtin_amdgcn_mfma_f32_16x16x32_bf16(cA1, cB3, acc[1][3], 0, 0, 0);
    cA0 = nA0; cA1 = nA1;
    cB0 = nB0; cB1 = nB1; cB2 = nB2; cB3 = nB3;
  }
  int which = n0 >> 9;
  int head = (n0 >> 6) & 7;
  short* dst = which == 0 ? Qh : (which == 1 ? Kh : Vh);
  float scale = which == 0 ? 0.125f : 1.0f;
#pragma unroll
  for (int mt = 0; mt < 2; mt++) {
#pragma unroll
    for (int r = 0; r < 4; r++) {
      int m = mw + mt * 16 + quad * 4 + r;
      int bb = m >> 11, s = m & 2047;
      size_t rowoff = ((size_t)(bb * 8 + head) * 2048 + s) * 64;
#pragma unroll
      for (int t = 0; t < 4; t++) {
        int hd = t * 16 + l16;
        float v = acc[mt][t][r] + bias[n0 + hd];
        dst[rowoff + hd] = f2bf(v * scale);
      }
    }
  }
}

// ---------------------------------------------------------------------------
// kpvp + local_attn fused.
// ---------------------------------------------------------------------------
__global__ __launch_bounds__(256, 4) void kpvp_local_kernel(
    const short* __restrict__ Kh, const short* __restrict__ Vh,
    const short* __restrict__ Wkpbf, const float* __restrict__ bkp,
    const short* __restrict__ W2bf, const float* __restrict__ cvec,
    short* __restrict__ Kph, float* __restrict__ Vpp,
    const short* __restrict__ Qh, float* __restrict__ ctxl) {
  int tid = threadIdx.x;
  __shared__ float Sloc[4][2][16][17];
  __shared__ float wloc[4][16][8];
  if (blockIdx.x < 256) {
    int m0 = blockIdx.x * 128;
    int wvv = tid >> 6, lane = tid & 63;
    int quad = lane >> 4, l16 = lane & 15;
    int mw = m0 + wvv * 32;
    {
      const short* ap0 = Kh + (size_t)(mw + l16) * 64 + quad * 8;
      const short* ap1 = ap0 + 16 * 64;
      const short* bp = Wkpbf + l16 * 64 + quad * 8;
      bf16x8 A00 = *(const bf16x8*)ap0, A01 = *(const bf16x8*)(ap0 + 32);
      bf16x8 A10 = *(const bf16x8*)ap1, A11 = *(const bf16x8*)(ap1 + 32);
      f32x4 acc[2][4] = {};
#pragma unroll
      for (int t = 0; t < 4; t++) {
        bf16x8 B0 = *(const bf16x8*)(bp + t * 16 * 64);
        bf16x8 B1 = *(const bf16x8*)(bp + t * 16 * 64 + 32);
        acc[0][t] = __builtin_amdgcn_mfma_f32_16x16x32_bf16(A00, B0, acc[0][t], 0, 0, 0);
        acc[0][t] = __builtin_amdgcn_mfma_f32_16x16x32_bf16(A01, B1, acc[0][t], 0, 0, 0);
        acc[1][t] = __builtin_amdgcn_mfma_f32_16x16x32_bf16(A10, B0, acc[1][t], 0, 0, 0);
        acc[1][t] = __builtin_amdgcn_mfma_f32_16x16x32_bf16(A11, B1, acc[1][t], 0, 0, 0);
      }
#pragma unroll
      for (int mt = 0; mt < 2; mt++)
#pragma unroll
        for (int r = 0; r < 4; r++) {
          int m = mw + mt * 16 + quad * 4 + r;
#pragma unroll
          for (int t = 0; t < 4; t++) {
            int n = t * 16 + l16;
            Kph[(size_t)m * 64 + n] = f2bf(acc[mt][t][r] + bkp[n]);
          }
        }
    }
    {
      const short* ap0 = Vh + (size_t)(mw + l16) * 64 + quad * 8;
      const short* ap1 = ap0 + 16 * 64;
      const short* bp = W2bf + l16 * 64 + quad * 8;
      bf16x8 A00 = *(const bf16x8*)ap0, A01 = *(const bf16x8*)(ap0 + 32);
      bf16x8 A10 = *(const bf16x8*)ap1, A11 = *(const bf16x8*)(ap1 + 32);
      f32x4 acc[2][4] = {};
#pragma unroll
      for (int t = 0; t < 4; t++) {
        bf16x8 B0 = *(const bf16x8*)(bp + t * 16 * 64);
        bf16x8 B1 = *(const bf16x8*)(bp + t * 16 * 64 + 32);
        acc[0][t] = __builtin_amdgcn_mfma_f32_16x16x32_bf16(A00, B0, acc[0][t], 0, 0, 0);
        acc[0][t] = __builtin_amdgcn_mfma_f32_16x16x32_bf16(A01, B1, acc[0][t], 0, 0, 0);
        acc[1][t] = __builtin_amdgcn_mfma_f32_16x16x32_bf16(A10, B0, acc[1][t], 0, 0, 0);
        acc[1][t] = __builtin_amdgcn_mfma_f32_16x16x32_bf16(A11, B1, acc[1][t], 0, 0, 0);
      }
#pragma unroll
      for (int mt = 0; mt < 2; mt++)
#pragma unroll
        for (int r = 0; r < 4; r++) {
          int m = mw + mt * 16 + quad * 4 + r;
#pragma unroll
          for (int t = 0; t < 4; t++) {
            int n = t * 16 + l16;
            Vpp[(size_t)m * 64 + n] = acc[mt][t][r] + cvec[n];
          }
        }
    }
    return;
  }
  // ---- local windowed attention ----
  int wv = tid >> 6;
  int tile = (blockIdx.x - 256) * 4 + wv;   // 0..2047
  int bh = tile >> 7;
  int q0 = (tile & 127) * 16;
  int lane = tid & 63;
  int quad = lane >> 4, l16 = lane & 15;

  const short* qbase = Qh + (size_t)(bh * 2048 + q0 + l16) * 64 + quad * 8;
  bf16x8 a0 = *(const bf16x8*)qbase;
  bf16x8 a1 = *(const bf16x8*)(qbase + 32);

  int k0a = min(max(q0 - 2 + l16, 0), 2047);
  int k1a = min(q0 + 6 + l16, 2047);
  const short* kb0 = Kh + (size_t)(bh * 2048 + k0a) * 64 + quad * 8;
  const short* kb1 = Kh + (size_t)(bh * 2048 + k1a) * 64 + quad * 8;
  bf16x8 B00 = *(const bf16x8*)kb0;
  bf16x8 B01 = *(const bf16x8*)(kb0 + 32);
  bf16x8 B10 = *(const bf16x8*)kb1;
  bf16x8 B11 = *(const bf16x8*)(kb1 + 32);
  f32x4 C0 = {0.f, 0.f, 0.f, 0.f};
  f32x4 C1 = {0.f, 0.f, 0.f, 0.f};
  C0 = __builtin_amdgcn_mfma_f32_16x16x32_bf16(a0, B00, C0, 0, 0, 0);
  C0 = __builtin_amdgcn_mfma_f32_16x16x32_bf16(a1, B01, C0, 0, 0, 0);
  C1 = __builtin_amdgcn_mfma_f32_16x16x32_bf16(a0, B10, C1, 0, 0, 0);
  C1 = __builtin_amdgcn_mfma_f32_16x16x32_bf16(a1, B11, C1, 0, 0, 0);
#pragma unroll
  for (int r = 0; r < 4; r++) {
    Sloc[wv][0][quad * 4 + r][l16] = C0[r];
    Sloc[wv][1][quad * 4 + r][l16] = C1[r];
  }
  __builtin_amdgcn_wave_barrier();
  if (lane < 16) {
    int q = lane;
    float sc[5];
    bool ok[5];
#pragma unroll
    for (int j = 0; j < 5; j++) {
      int offq = q + j - 2;
      int sg = q0 + offq;
      ok[j] = (sg >= 0 && sg < SS);
      int t = offq <= 13 ? 0 : 1;
      int col = t ? offq - 6 : offq + 2;
      sc[j] = ok[j] ? Sloc[wv][t][q][col] : -3.0e38f;
    }
    float m = -3.0e38f;
#pragma unroll
    for (int j = 0; j < 5; j++) m = fmaxf(m, sc[j]);
    float e[5], l = 0.f;
#pragma unroll
    for (int j = 0; j < 5; j++) {
      e[j] = ok[j] ? __expf(sc[j] - m) : 0.f;
      l += e[j];
    }
    float inv = 1.f / l;
#pragma unroll
    for (int j = 0; j < 5; j++) wloc[wv][q][j] = e[j] * inv;
  }
  __builtin_amdgcn_wave_barrier();
  {
    int q = lane >> 2, jb = (lane & 3) * 16;
    int s = q0 + q;
    float acc[16] = {};
#pragma unroll
    for (int j = 0; j < 5; j++) {
      int sg = s + j - 2;
      if (sg >= 0 && sg < SS) {
        float w = wloc[wv][q][j];
        const short* vr = Vh + (size_t)(bh * 2048 + sg) * 64 + jb;
#pragma unroll
        for (int u = 0; u < 16; u += 4) {
          short4 v4 = *(const short4*)(vr + u);
          acc[u + 0] += w * bf2f(v4.x);
          acc[u + 1] += w * bf2f(v4.y);
          acc[u + 2] += w * bf2f(v4.z);
          acc[u + 3] += w * bf2f(v4.w);
        }
      }
    }
    float* orow = ctxl + (size_t)(bh * 2048 + s) * 64 + jb;
#pragma unroll
    for (int u = 0; u < 16; u += 4)
      *(float4*)(orow + u) =
          make_float4(acc[u], acc[u + 1], acc[u + 2], acc[u + 3]);
  }
}

// ---------------------------------------------------------------------------
// global sparse attention — v10: 512 blocks x 4 waves (2 blocks/CU) so two
// INDEPENDENT barrier domains per CU overlap each other's chunk-barrier
// drains (r9: grid=256 -> one 8-wave domain/CU, occupancy capped 20%, 65%
// stall). Staging per thread: 64B (4x bf16x8). Same swizzle/selection math
// as the r8-verified kernel.
// ---------------------------------------------------------------------------
__global__ __launch_bounds__(256, 2) void global_attn(
    const short* __restrict__ Qh, const short* __restrict__ Kph,
    const float* __restrict__ Vpp, const float* __restrict__ ctxl,
    short* __restrict__ ctxcb) {
  int tid = threadIdx.x;
  int wv = tid >> 6;
  int lane = tid & 63;
  int quad = lane >> 4, l16 = lane & 15;
  int p = blockIdx.x;                       // 0..511
  int bh = (p & 7) * 2 + ((p >> 3) & 1);    // XCD-affine
  int seg = p >> 4;                         // 0..31
  int tile = seg * 4 + wv;                  // tile within bh: 0..127
  int q0 = tile * 16;

  __shared__ short Ks[2][128][64];          // 32 KB, col-swizzled
  __shared__ float twl[4][16][17];
  __shared__ int   txl[4][16][17];

  const short* qbase = Qh + (size_t)(bh * 2048 + q0 + l16) * 64 + quad * 8;
  bf16x8 a0 = *(const bf16x8*)qbase;
  bf16x8 a1 = *(const bf16x8*)(qbase + 32);

  const short* kpanel = Kph + (size_t)bh * (2048 * 64);

  unsigned er[4][8];
#pragma unroll
  for (int a = 0; a < 4; a++)
#pragma unroll
    for (int j = 0; j < 8; j++) er[a][j] = 0u;

  auto insert8 = [&](unsigned (&e)[8], unsigned cand) {
    unsigned n0, n1, n2, n3, n4, n5, n6, n7;
    asm("v_max_u32 %0, %1, %2" : "=v"(n0) : "v"(e[0]), "v"(cand));
    asm("v_med3_u32 %0, %1, %2, %3" : "=v"(n1) : "v"(e[0]), "v"(e[1]), "v"(cand));
    asm("v_med3_u32 %0, %1, %2, %3" : "=v"(n2) : "v"(e[1]), "v"(e[2]), "v"(cand));
    asm("v_med3_u32 %0, %1, %2, %3" : "=v"(n3) : "v"(e[2]), "v"(e[3]), "v"(cand));
    asm("v_med3_u32 %0, %1, %2, %3" : "=v"(n4) : "v"(e[3]), "v"(e[4]), "v"(cand));
    asm("v_med3_u32 %0, %1, %2, %3" : "=v"(n5) : "v"(e[4]), "v"(e[5]), "v"(cand));
    asm("v_med3_u32 %0, %1, %2, %3" : "=v"(n6) : "v"(e[5]), "v"(e[6]), "v"(cand));
    asm("v_med3_u32 %0, %1, %2, %3" : "=v"(n7) : "v"(e[6]), "v"(e[7]), "v"(cand));
    e[0] = n0; e[1] = n1; e[2] = n2; e[3] = n3;
    e[4] = n4; e[5] = n5; e[6] = n6; e[7] = n7;
  };
  auto mkcand = [&](float s, int idxr) -> unsigned {
    unsigned u = __float_as_uint(s);
    u ^= ((unsigned)((int)u >> 31)) | 0x80000000u;
    return (u & 0xFFFFF800u) | (unsigned)idxr;
  };

  // Staging: thread t covers 64B of the 16KB chunk (coalesced).
  int skey = tid >> 1;                  // 0..127
  int scol = (tid & 1) * 32;            // shorts
  int ssw = (skey & 7) << 3;            // swizzle (16B units as shorts)
  const short* gsrc = kpanel + (size_t)tid * 32;

  {
    bf16x8 c0 = *(const bf16x8*)gsrc;
    bf16x8 c1 = *(const bf16x8*)(gsrc + 8);
    bf16x8 c2 = *(const bf16x8*)(gsrc + 16);
    bf16x8 c3 = *(const bf16x8*)(gsrc + 24);
    short* dst = &Ks[0][skey][0];
    *(bf16x8*)(dst + ((scol + 0) ^ ssw)) = c0;
    *(bf16x8*)(dst + ((scol + 8) ^ ssw)) = c1;
    *(bf16x8*)(dst + ((scol + 16) ^ ssw)) = c2;
    *(bf16x8*)(dst + ((scol + 24) ^ ssw)) = c3;
  }
  __syncthreads();

  int rsw = ((l16 & 7) << 3);
#pragma unroll 1
  for (int ck = 0; ck < 16; ck++) {
    int cb = ck & 1, nb = cb ^ 1;
    bf16x8 p0, p1, p2, p3;
    if (ck < 15) {
      const short* ng = kpanel + (size_t)(ck + 1) * 8192 + tid * 32;
      p0 = *(const bf16x8*)ng;
      p1 = *(const bf16x8*)(ng + 8);
      p2 = *(const bf16x8*)(ng + 16);
      p3 = *(const bf16x8*)(ng + 24);
    }
#pragma unroll
    for (int gg = 0; gg < 4; gg++) {
      int k0 = gg * 32 + l16;
      int k1 = k0 + 16;
      const short* s0 = &Ks[cb][k0][0];
      const short* s1 = &Ks[cb][k1][0];
      bf16x8 B00 = *(const bf16x8*)(s0 + ((quad * 8) ^ rsw));
      bf16x8 B01 = *(const bf16x8*)(s0 + ((quad * 8 + 32) ^ rsw));
      bf16x8 B10 = *(const bf16x8*)(s1 + ((quad * 8) ^ rsw));
      bf16x8 B11 = *(const bf16x8*)(s1 + ((quad * 8 + 32) ^ rsw));
      f32x4 C0 = {0.f, 0.f, 0.f, 0.f};
      f32x4 C1 = {0.f, 0.f, 0.f, 0.f};
      C0 = __builtin_amdgcn_mfma_f32_16x16x32_bf16(a0, B00, C0, 0, 0, 0);
      C0 = __builtin_amdgcn_mfma_f32_16x16x32_bf16(a1, B01, C0, 0, 0, 0);
      C1 = __builtin_amdgcn_mfma_f32_16x16x32_bf16(a0, B10, C1, 0, 0, 0);
      C1 = __builtin_amdgcn_mfma_f32_16x16x32_bf16(a1, B11, C1, 0, 0, 0);
      int idxr0 = 2047 - (ck * 128 + gg * 32) - l16;
      int idxr1 = idxr0 - 16;
      insert8(er[0], mkcand(C0[0], idxr0));
      insert8(er[1], mkcand(C0[1], idxr0));
      insert8(er[2], mkcand(C0[2], idxr0));
      insert8(er[3], mkcand(C0[3], idxr0));
      insert8(er[0], mkcand(C1[0], idxr1));
      insert8(er[1], mkcand(C1[1], idxr1));
      insert8(er[2], mkcand(C1[2], idxr1));
      insert8(er[3], mkcand(C1[3], idxr1));
    }
    __syncthreads();
    if (ck < 15) {
      short* dst = &Ks[nb][skey][0];
      *(bf16x8*)(dst + ((scol + 0) ^ ssw)) = p0;
      *(bf16x8*)(dst + ((scol + 8) ^ ssw)) = p1;
      *(bf16x8*)(dst + ((scol + 16) ^ ssw)) = p2;
      *(bf16x8*)(dst + ((scol + 24) ^ ssw)) = p3;
      __syncthreads();
    }
  }

  // Extraction + inline softmax (verified form).
  {
    float mval[4] = {0.f, 0.f, 0.f, 0.f};
    float lsum[4] = {0.f, 0.f, 0.f, 0.f};
    float myev[4] = {0.f, 0.f, 0.f, 0.f};
    int myki[4] = {0, 0, 0, 0};
#pragma unroll
    for (int t = 0; t < 16; t++) {
#pragma unroll
      for (int a = 0; a < 4; a++) {
        unsigned w = er[a][0];
#pragma unroll
        for (int mm = 1; mm <= 8; mm <<= 1) {
          unsigned o = (unsigned)__shfl_xor((int)w, mm);
          w = w > o ? w : o;
        }
        bool pop = (er[a][0] == w);
#pragma unroll
        for (int j = 0; j < 7; j++) er[a][j] = pop ? er[a][j + 1] : er[a][j];
        er[a][7] = pop ? 0u : er[a][7];
        unsigned wb = w & 0xFFFFF800u;
        unsigned uu = (w & 0x80000000u) ? (wb ^ 0x80000000u) : ~wb;
        float sv = (w == 0u) ? -1.0e30f : __uint_as_float(uu);
        if (t == 0) mval[a] = sv;
        float ex = __expf(sv - mval[a]);
        lsum[a] += ex;
        if (l16 == t) { myev[a] = ex; myki[a] = 2047 - (int)(w & 0x7FFu); }
      }
    }
#pragma unroll
    for (int a = 0; a < 4; a++) {
      twl[wv][quad * 4 + a][l16] = myev[a] / lsum[a];
      txl[wv][quad * 4 + a][l16] = myki[a];
    }
  }
  __builtin_amdgcn_wave_barrier();

  // Per-wave weighted gather of prefolded Vpp rows; combine with local ctx.
  {
    int q = lane >> 2, d0 = (lane & 3) * 16;
    int b = bh >> 3, hh = bh & 7;
    const float* vball = Vpp + (size_t)bh * (2048 * 64) + d0;
    float acc[16];
#pragma unroll
    for (int u = 0; u < 16; u++) acc[u] = 0.f;
#pragma unroll 4
    for (int j = 0; j < 16; j++) {
      float w = twl[wv][q][j];
      const float* vr = vball + (size_t)txl[wv][q][j] * 64;
#pragma unroll
      for (int u = 0; u < 16; u += 4) {
        float4 v = *(const float4*)(vr + u);
        acc[u + 0] += w * v.x;
        acc[u + 1] += w * v.y;
        acc[u + 2] += w * v.z;
        acc[u + 3] += w * v.w;
      }
    }
    int s = q0 + q;
    const float* lrow = ctxl + (size_t)(bh * 2048 + s) * 64 + d0;
    short* orow = ctxcb + (size_t)(b * 2048 + s) * 512 + hh * 64 + d0;
#pragma unroll
    for (int u = 0; u < 16; u += 4) {
      float4 lv = *(const float4*)(lrow + u);
      short4 o;
      o.x = f2bf(0.5f * (lv.x + acc[u + 0]));
      o.y = f2bf(0.5f * (lv.y + acc[u + 1]));
      o.z = f2bf(0.5f * (lv.z + acc[u + 2]));
      o.w = f2bf(0.5f * (lv.w + acc[u + 3]));
      *(short4*)(orow + u) = o;
    }
  }
}

// ---------------------------------------------------------------------------
// MFMA Wo gemm: 128-row blocks, wave = 32 rows. Residual from bf16 hbf.
// ---------------------------------------------------------------------------
__global__ __launch_bounds__(256, 4) void gemm_wo(
    const short* __restrict__ Abf, const short* __restrict__ Wbf,
    const float* __restrict__ bo, const short* __restrict__ hbf,
    float* __restrict__ outp) {
  int m0 = blockIdx.x * 128;
  int n0 = blockIdx.y * 64;
  int tid = threadIdx.x;
  int wvv = tid >> 6, lane = tid & 63;
  int quad = lane >> 4, l16 = lane & 15;
  int mw = m0 + wvv * 32;
  const short* ap0 = Abf + (size_t)(mw + l16) * 512 + quad * 8;
  const short* ap1 = ap0 + 16 * 512;
  const short* bp = Wbf + (size_t)(n0 + l16) * 512 + quad * 8;
  f32x4 acc[2][4] = {};
  bf16x8 cA0 = *(const bf16x8*)ap0;
  bf16x8 cA1 = *(const bf16x8*)ap1;
  bf16x8 cB0 = *(const bf16x8*)(bp + 0 * 16 * 512);
  bf16x8 cB1 = *(const bf16x8*)(bp + 1 * 16 * 512);
  bf16x8 cB2 = *(const bf16x8*)(bp + 2 * 16 * 512);
  bf16x8 cB3 = *(const bf16x8*)(bp + 3 * 16 * 512);
#pragma unroll 2
  for (int ks = 0; ks < 16; ks++) {
    int offn = (ks + 1 < 16 ? ks + 1 : 15) * 32;
    bf16x8 nA0 = *(const bf16x8*)(ap0 + offn);
    bf16x8 nA1 = *(const bf16x8*)(ap1 + offn);
    bf16x8 nB0 = *(const bf16x8*)(bp + 0 * 16 * 512 + offn);
    bf16x8 nB1 = *(const bf16x8*)(bp + 1 * 16 * 512 + offn);
    bf16x8 nB2 = *(const bf16x8*)(bp + 2 * 16 * 512 + offn);
    bf16x8 nB3 = *(const bf16x8*)(bp + 3 * 16 * 512 + offn);
    acc[0][0] = __builtin_amdgcn_mfma_f32_16x16x32_bf16(cA0, cB0, acc[0][0], 0, 0, 0);
    acc[1][0] = __builtin_amdgcn_mfma_f32_16x16x32_bf16(cA1, cB0, acc[1][0], 0, 0, 0);
    acc[0][1] = __builtin_amdgcn_mfma_f32_16x16x32_bf16(cA0, cB1, acc[0][1], 0, 0, 0);
    acc[1][1] = __builtin_amdgcn_mfma_f32_16x16x32_bf16(cA1, cB1, acc[1][1], 0, 0, 0);
    acc[0][2] = __builtin_amdgcn_mfma_f32_16x16x32_bf16(cA0, cB2, acc[0][2], 0, 0, 0);
    acc[1][2] = __builtin_amdgcn_mfma_f32_16x16x32_bf16(cA1, cB2, acc[1][2], 0, 0, 0);
    acc[0][3] = __builtin_amdgcn_mfma_f32_16x16x32_bf16(cA0, cB3, acc[0][3], 0, 0, 0);
    acc[1][3] = __builtin_amdgcn_mfma_f32_16x16x32_bf16(cA1, cB3, acc[1][3], 0, 0, 0);
    cA0 = nA0; cA1 = nA1;
    cB0 = nB0; cB1 = nB1; cB2 = nB2; cB3 = nB3;
  }
#pragma unroll
  for (int mt = 0; mt < 2; mt++) {
#pragma unroll
    for (int r = 0; r < 4; r++) {
      int m = mw + mt * 16 + quad * 4 + r;
#pragma unroll
      for (int t = 0; t < 4; t++) {
        int n = n0 + t * 16 + l16;
        outp[(size_t)m * 512 + n] =
            acc[mt][t][r] + bo[n] + bf2f(hbf[(size_t)m * 512 + n]);
      }
    }
  }
}

// ---------------------------------------------------------------------------
// layernorm in place on d_out, one block per row
// ---------------------------------------------------------------------------
__global__ __launch_bounds__(256) void ln_kernel(float* __restrict__ o,
                                                 const float* __restrict__ g,
                                                 const float* __restrict__ bb) {
  int row = blockIdx.x;
  int tid = threadIdx.x;
  float v0 = o[row * 512 + tid];
  float v1 = o[row * 512 + 256 + tid];
  float s = v0 + v1;
  float s2 = v0 * v0 + v1 * v1;
#pragma unroll
  for (int off = 1; off < 64; off <<= 1) {
    s += __shfl_xor(s, off);
    s2 += __shfl_xor(s2, off);
  }
  __shared__ float ps[4], ps2[4];
  int w = tid >> 6;
  if ((tid & 63) == 0) { ps[w] = s; ps2[w] = s2; }
  __syncthreads();
  float S = ps[0] + ps[1] + ps[2] + ps[3];
  float S2 = ps2[0] + ps2[1] + ps2[2] + ps2[3];
  float mu = S * (1.f / 512.f);
  float var = S2 * (1.f / 512.f) - mu * mu;
  float inv = rsqrtf(var + 1e-5f);
  o[row * 512 + tid] = (v0 - mu) * inv * g[tid] + bb[tid];
  o[row * 512 + 256 + tid] = (v1 - mu) * inv * g[tid + 256] + bb[tid + 256];
}

// ---------------------------------------------------------------------------
extern "C" void kernel_launch(void* const* d_in, const int* in_sizes, int n_in,
                              void* d_out, int out_size, void* d_ws,
                              size_t ws_size, hipStream_t stream) {
  const float* x   = (const float*)d_in[0];
  const float* w1  = (const float*)d_in[1];
  const float* b1  = (const float*)d_in[2];
  const float* w2  = (const float*)d_in[3];
  const float* b2  = (const float*)d_in[4];
  const float* w3  = (const float*)d_in[5];
  const float* b3  = (const float*)d_in[6];
  const float* Wq  = (const float*)d_in[7];
  const float* bq  = (const float*)d_in[8];
  const float* Wk  = (const float*)d_in[9];
  const float* bk  = (const float*)d_in[10];
  const float* Wv  = (const float*)d_in[11];
  const float* bv  = (const float*)d_in[12];
  const float* Wkp = (const float*)d_in[13];
  const float* bkp = (const float*)d_in[14];
  const float* Wvp = (const float*)d_in[15];
  const float* bvp = (const float*)d_in[16];
  const float* Wo  = (const float*)d_in[17];
  const float* bo  = (const float*)d_in[18];
  const float* lng = (const float*)d_in[19];
  const float* lnb = (const float*)d_in[20];

  float* p = (float*)d_ws;
  short* Wallbf = (short*)p;  p += 786432;
  float* ball   = p;          p += 2048;
  short* Wobf   = (short*)p;  p += 262144;
  short* Wkpbf  = (short*)p;  p += 4096;
  short* W2bf   = (short*)p;  p += 4096;
  float* cvec   = p;          p += 64;
  short* xbfp   = (short*)p;  p += 262912;
  short* Wcbf   = (short*)p;  p += 229376;
  float* bcat   = p;          p += 512;
  short* hbf    = (short*)p;  p += 1048576;
  short* Qh     = (short*)p;  p += 1048576;
  short* Kh     = (short*)p;  p += 1048576;
  short* Vh     = (short*)p;  p += 1048576;
  short* Kph    = (short*)p;  p += 1048576;
  float* Vpp    = p;          p += 2097152;
  float* ctxl   = p;          p += 2097152;
  short* ctxcb  = (short*)p;  p += 1048576;
  float* outF   = (float*)d_out;

  prep_kernel<<<512, 256, 0, stream>>>(x, w1, b1, w2, b2, w3, b3, Wq, Wk, Wv,
                                       bq, bk, bv, Wo, Wkp, Wvp, bvp, Wallbf,
                                       ball, Wobf, Wkpbf, W2bf, cvec, xbfp,
                                       Wcbf, bcat);
  {
    dim3 g(32, 8);
    gemm_conv<<<g, 256, 0, stream>>>(xbfp, Wcbf, bcat, hbf);
  }
  {
    dim3 g(32, 24);
    gemm_qkv<<<g, 256, 0, stream>>>(hbf, Wallbf, ball, Qh, Kh, Vh);
  }
  kpvp_local_kernel<<<768, 256, 0, stream>>>(Kh, Vh, Wkpbf, bkp, W2bf, cvec,
                                             Kph, Vpp, Qh, ctxl);
  global_attn<<<512, 256, 0, stream>>>(Qh, Kph, Vpp, ctxl, ctxcb);
  {
    dim3 g(32, 8);
    gemm_wo<<<g, 256, 0, stream>>>(ctxcb, Wobf, bo, hbf, outF);
  }
  ln_kernel<<<4096, 256, 0, stream>>>(outF, lng, lnb);
}

// Round 11
// 230.177 us; speedup vs baseline: 1.2720x; 1.0362x over previous
//
#include <hip/hip_runtime.h>
#include <hip/hip_bf16.h>

#define BB 2
#define SS 2048
#define INC 64
#define HIDN 512
#define NHH 8
#define HDD 64
#define SP 2054   // padded seq rows per batch (3 zero + 2048 + 3 zero)

typedef __attribute__((ext_vector_type(8))) short bf16x8;
typedef __attribute__((ext_vector_type(4))) float f32x4;

__device__ __forceinline__ short f2bf(float f) {
  union { __hip_bfloat16 h; short s; } u;
  u.h = __float2bfloat16(f);
  return u.s;
}
__device__ __forceinline__ float bf2f(short s) {
  return __uint_as_float(((unsigned)(unsigned short)s) << 16);
}

// ---------------------------------------------------------------------------
// prep: all weight conversions + conv GEMM packing.
// ---------------------------------------------------------------------------
__global__ __launch_bounds__(256) void prep_kernel(
    const float* __restrict__ x, const float* __restrict__ w1,
    const float* __restrict__ b1, const float* __restrict__ w2,
    const float* __restrict__ b2, const float* __restrict__ w3,
    const float* __restrict__ b3, const float* __restrict__ Wq,
    const float* __restrict__ Wk_, const float* __restrict__ Wv_,
    const float* __restrict__ bq, const float* __restrict__ bk_,
    const float* __restrict__ bv_, const float* __restrict__ Wo,
    const float* __restrict__ Wkp, const float* __restrict__ Wvp,
    const float* __restrict__ bvp, short* __restrict__ Wallbf,
    float* __restrict__ ball, short* __restrict__ Wobf,
    short* __restrict__ Wkpbf, short* __restrict__ W2bf,
    float* __restrict__ cvec, short* __restrict__ xbfp,
    short* __restrict__ Wcbf, float* __restrict__ bcat) {
  int i0 = blockIdx.x * 256 + threadIdx.x;
  int stride = gridDim.x * 256;
  for (int idx = i0; idx < 786432; idx += stride) {
    float v;
    if (idx < 262144)      v = Wq[idx];
    else if (idx < 524288) v = Wk_[idx - 262144];
    else                   v = Wv_[idx - 524288];
    Wallbf[idx] = f2bf(v);
  }
  for (int idx = i0; idx < 262144; idx += stride) Wobf[idx] = f2bf(Wo[idx]);
  for (int idx = i0; idx < BB * SP * 64; idx += stride) {
    int row = idx >> 6, ci = idx & 63;
    int b = row / SP, pr = row - b * SP;
    int sg = pr - 3;
    float v = (sg >= 0 && sg < SS) ? x[(b * SS + sg) * 64 + ci] : 0.f;
    xbfp[idx] = f2bf(v);
  }
  for (int idx = i0; idx < 512 * 448; idx += stride) {
    int c = idx / 448;
    int rem = idx - c * 448;
    int t = rem >> 6, ci = rem & 63;
    float v = 0.f;
    if (c < 171) {
      int k = t - 2;
      if (k >= 0 && k < 3) v = w1[(c * 64 + ci) * 3 + k];
    } else if (c < 342) {
      int k = t - 1;
      if (k >= 0 && k < 5) v = w2[((c - 171) * 64 + ci) * 5 + k];
    } else {
      v = w3[((c - 342) * 64 + ci) * 7 + t];
    }
    Wcbf[idx] = f2bf(v);
  }
  for (int idx = i0; idx < 4096; idx += stride) {
    Wkpbf[idx] = f2bf(Wkp[idx]);
    int j = idx >> 6, d = idx & 63;
    float s = 0.f;
#pragma unroll 8
    for (int i = 0; i < 64; i++) s += Wvp[j * 64 + i] * Wvp[i * 64 + d];
    W2bf[idx] = f2bf(s);
  }
  if (i0 < 1536) {
    float v;
    if (i0 < 512)       v = bq[i0];
    else if (i0 < 1024) v = bk_[i0 - 512];
    else                v = bv_[i0 - 1024];
    ball[i0] = v;
  }
  if (i0 < 512) {
    float v;
    if (i0 < 171)      v = b1[i0];
    else if (i0 < 342) v = b2[i0 - 171];
    else               v = b3[i0 - 342];
    bcat[i0] = v;
  }
  if (i0 < 64) {
    float s = bvp[i0];
#pragma unroll 8
    for (int i = 0; i < 64; i++) s += bvp[i] * Wvp[i0 * 64 + i];
    cvec[i0] = s;
  }
}

// ---------------------------------------------------------------------------
// conv as MFMA GEMM: M=4096 N=512 K=448, contiguous im2col rows in xbfp.
// ---------------------------------------------------------------------------
__global__ __launch_bounds__(256, 4) void gemm_conv(
    const short* __restrict__ xbfp, const short* __restrict__ Wcbf,
    const float* __restrict__ bcat, short* __restrict__ hbf) {
  int m0 = blockIdx.x * 128;
  int n0 = blockIdx.y * 64;
  int tid = threadIdx.x;
  int wvv = tid >> 6, lane = tid & 63;
  int quad = lane >> 4, l16 = lane & 15;
  int mw = m0 + wvv * 32;
  int r0 = mw + l16, r1 = r0 + 16;
  int b0 = r0 >> 11, s0 = r0 & 2047;
  int b1 = r1 >> 11, s1 = r1 & 2047;
  const short* ap0 = xbfp + (size_t)(b0 * SP + s0) * 64 + quad * 8;
  const short* ap1 = xbfp + (size_t)(b1 * SP + s1) * 64 + quad * 8;
  const short* bp = Wcbf + (size_t)(n0 + l16) * 448 + quad * 8;
  f32x4 acc[2][4] = {};
  bf16x8 cA0 = *(const bf16x8*)ap0;
  bf16x8 cA1 = *(const bf16x8*)ap1;
  bf16x8 cB0 = *(const bf16x8*)(bp + 0 * 16 * 448);
  bf16x8 cB1 = *(const bf16x8*)(bp + 1 * 16 * 448);
  bf16x8 cB2 = *(const bf16x8*)(bp + 2 * 16 * 448);
  bf16x8 cB3 = *(const bf16x8*)(bp + 3 * 16 * 448);
#pragma unroll 2
  for (int ks = 0; ks < 14; ks++) {
    int offn = (ks + 1 < 14 ? ks + 1 : 13) * 32;
    bf16x8 nA0 = *(const bf16x8*)(ap0 + offn);
    bf16x8 nA1 = *(const bf16x8*)(ap1 + offn);
    bf16x8 nB0 = *(const bf16x8*)(bp + 0 * 16 * 448 + offn);
    bf16x8 nB1 = *(const bf16x8*)(bp + 1 * 16 * 448 + offn);
    bf16x8 nB2 = *(const bf16x8*)(bp + 2 * 16 * 448 + offn);
    bf16x8 nB3 = *(const bf16x8*)(bp + 3 * 16 * 448 + offn);
    acc[0][0] = __builtin_amdgcn_mfma_f32_16x16x32_bf16(cA0, cB0, acc[0][0], 0, 0, 0);
    acc[1][0] = __builtin_amdgcn_mfma_f32_16x16x32_bf16(cA1, cB0, acc[1][0], 0, 0, 0);
    acc[0][1] = __builtin_amdgcn_mfma_f32_16x16x32_bf16(cA0, cB1, acc[0][1], 0, 0, 0);
    acc[1][1] = __builtin_amdgcn_mfma_f32_16x16x32_bf16(cA1, cB1, acc[1][1], 0, 0, 0);
    acc[0][2] = __builtin_amdgcn_mfma_f32_16x16x32_bf16(cA0, cB2, acc[0][2], 0, 0, 0);
    acc[1][2] = __builtin_amdgcn_mfma_f32_16x16x32_bf16(cA1, cB2, acc[1][2], 0, 0, 0);
    acc[0][3] = __builtin_amdgcn_mfma_f32_16x16x32_bf16(cA0, cB3, acc[0][3], 0, 0, 0);
    acc[1][3] = __builtin_amdgcn_mfma_f32_16x16x32_bf16(cA1, cB3, acc[1][3], 0, 0, 0);
    cA0 = nA0; cA1 = nA1;
    cB0 = nB0; cB1 = nB1; cB2 = nB2; cB3 = nB3;
  }
#pragma unroll
  for (int mt = 0; mt < 2; mt++) {
#pragma unroll
    for (int r = 0; r < 4; r++) {
      int m = mw + mt * 16 + quad * 4 + r;
#pragma unroll
      for (int t = 0; t < 4; t++) {
        int n = n0 + t * 16 + l16;
        float v = fmaxf(acc[mt][t][r] + bcat[n], 0.f);
        hbf[(size_t)m * 512 + n] = f2bf(v);
      }
    }
  }
}

// ---------------------------------------------------------------------------
// MFMA QKV gemm: 128-row blocks, wave = 32 rows x 64 cols.
// ---------------------------------------------------------------------------
__global__ __launch_bounds__(256, 4) void gemm_qkv(
    const short* __restrict__ Abf, const short* __restrict__ Wbf,
    const float* __restrict__ bias, short* __restrict__ Qh,
    short* __restrict__ Kh, short* __restrict__ Vh) {
  int m0 = blockIdx.x * 128;
  int n0 = blockIdx.y * 64;
  int tid = threadIdx.x;
  int wvv = tid >> 6, lane = tid & 63;
  int quad = lane >> 4, l16 = lane & 15;
  int mw = m0 + wvv * 32;
  const short* ap0 = Abf + (size_t)(mw + l16) * 512 + quad * 8;
  const short* ap1 = ap0 + 16 * 512;
  const short* bp = Wbf + (size_t)(n0 + l16) * 512 + quad * 8;
  f32x4 acc[2][4] = {};
  bf16x8 cA0 = *(const bf16x8*)ap0;
  bf16x8 cA1 = *(const bf16x8*)ap1;
  bf16x8 cB0 = *(const bf16x8*)(bp + 0 * 16 * 512);
  bf16x8 cB1 = *(const bf16x8*)(bp + 1 * 16 * 512);
  bf16x8 cB2 = *(const bf16x8*)(bp + 2 * 16 * 512);
  bf16x8 cB3 = *(const bf16x8*)(bp + 3 * 16 * 512);
#pragma unroll 2
  for (int ks = 0; ks < 16; ks++) {
    int offn = (ks + 1 < 16 ? ks + 1 : 15) * 32;
    bf16x8 nA0 = *(const bf16x8*)(ap0 + offn);
    bf16x8 nA1 = *(const bf16x8*)(ap1 + offn);
    bf16x8 nB0 = *(const bf16x8*)(bp + 0 * 16 * 512 + offn);
    bf16x8 nB1 = *(const bf16x8*)(bp + 1 * 16 * 512 + offn);
    bf16x8 nB2 = *(const bf16x8*)(bp + 2 * 16 * 512 + offn);
    bf16x8 nB3 = *(const bf16x8*)(bp + 3 * 16 * 512 + offn);
    acc[0][0] = __builtin_amdgcn_mfma_f32_16x16x32_bf16(cA0, cB0, acc[0][0], 0, 0, 0);
    acc[1][0] = __builtin_amdgcn_mfma_f32_16x16x32_bf16(cA1, cB0, acc[1][0], 0, 0, 0);
    acc[0][1] = __builtin_amdgcn_mfma_f32_16x16x32_bf16(cA0, cB1, acc[0][1], 0, 0, 0);
    acc[1][1] = __builtin_amdgcn_mfma_f32_16x16x32_bf16(cA1, cB1, acc[1][1], 0, 0, 0);
    acc[0][2] = __builtin_amdgcn_mfma_f32_16x16x32_bf16(cA0, cB2, acc[0][2], 0, 0, 0);
    acc[1][2] = __builtin_amdgcn_mfma_f32_16x16x32_bf16(cA1, cB2, acc[1][2], 0, 0, 0);
    acc[0][3] = __builtin_amdgcn_mfma_f32_16x16x32_bf16(cA0, cB3, acc[0][3], 0, 0, 0);
    acc[1][3] = __builtin_amdgcn_mfma_f32_16x16x32_bf16(cA1, cB3, acc[1][3], 0, 0, 0);
    cA0 = nA0; cA1 = nA1;
    cB0 = nB0; cB1 = nB1; cB2 = nB2; cB3 = nB3;
  }
  int which = n0 >> 9;
  int head = (n0 >> 6) & 7;
  short* dst = which == 0 ? Qh : (which == 1 ? Kh : Vh);
  float scale = which == 0 ? 0.125f : 1.0f;
#pragma unroll
  for (int mt = 0; mt < 2; mt++) {
#pragma unroll
    for (int r = 0; r < 4; r++) {
      int m = mw + mt * 16 + quad * 4 + r;
      int bb = m >> 11, s = m & 2047;
      size_t rowoff = ((size_t)(bb * 8 + head) * 2048 + s) * 64;
#pragma unroll
      for (int t = 0; t < 4; t++) {
        int hd = t * 16 + l16;
        float v = acc[mt][t][r] + bias[n0 + hd];
        dst[rowoff + hd] = f2bf(v * scale);
      }
    }
  }
}

// ---------------------------------------------------------------------------
// kpvp + local_attn fused.
// v11: K-projection result is stored in MFMA-FRAGMENT order (Kfrag) so the
// global_attn B-loads are 16B/lane fully coalesced:
// Kfrag offset(m,n) = (m>>4)*1024 + (n>>5)*512 + (((n&31)>>3)*16+(m&15))*8
//                     + (n&7)   [shorts]
// ---------------------------------------------------------------------------
__global__ __launch_bounds__(256, 4) void kpvp_local_kernel(
    const short* __restrict__ Kh, const short* __restrict__ Vh,
    const short* __restrict__ Wkpbf, const float* __restrict__ bkp,
    const short* __restrict__ W2bf, const float* __restrict__ cvec,
    short* __restrict__ Kfrag, float* __restrict__ Vpp,
    const short* __restrict__ Qh, float* __restrict__ ctxl) {
  int tid = threadIdx.x;
  __shared__ float Sloc[4][2][16][17];
  __shared__ float wloc[4][16][8];
  if (blockIdx.x < 256) {
    int m0 = blockIdx.x * 128;
    int wvv = tid >> 6, lane = tid & 63;
    int quad = lane >> 4, l16 = lane & 15;
    int mw = m0 + wvv * 32;
    {
      const short* ap0 = Kh + (size_t)(mw + l16) * 64 + quad * 8;
      const short* ap1 = ap0 + 16 * 64;
      const short* bp = Wkpbf + l16 * 64 + quad * 8;
      bf16x8 A00 = *(const bf16x8*)ap0, A01 = *(const bf16x8*)(ap0 + 32);
      bf16x8 A10 = *(const bf16x8*)ap1, A11 = *(const bf16x8*)(ap1 + 32);
      f32x4 acc[2][4] = {};
#pragma unroll
      for (int t = 0; t < 4; t++) {
        bf16x8 B0 = *(const bf16x8*)(bp + t * 16 * 64);
        bf16x8 B1 = *(const bf16x8*)(bp + t * 16 * 64 + 32);
        acc[0][t] = __builtin_amdgcn_mfma_f32_16x16x32_bf16(A00, B0, acc[0][t], 0, 0, 0);
        acc[0][t] = __builtin_amdgcn_mfma_f32_16x16x32_bf16(A01, B1, acc[0][t], 0, 0, 0);
        acc[1][t] = __builtin_amdgcn_mfma_f32_16x16x32_bf16(A10, B0, acc[1][t], 0, 0, 0);
        acc[1][t] = __builtin_amdgcn_mfma_f32_16x16x32_bf16(A11, B1, acc[1][t], 0, 0, 0);
      }
#pragma unroll
      for (int mt = 0; mt < 2; mt++)
#pragma unroll
        for (int r = 0; r < 4; r++) {
          int m = mw + mt * 16 + quad * 4 + r;
          int m15 = m & 15;
          size_t gbase = (size_t)(m >> 4) * 1024;
#pragma unroll
          for (int t = 0; t < 4; t++) {
            int n = t * 16 + l16;
            short val = f2bf(acc[mt][t][r] + bkp[n]);
            Kfrag[gbase + (size_t)(n >> 5) * 512 +
                  ((((n & 31) >> 3) * 16 + m15) << 3) + (n & 7)] = val;
          }
        }
    }
    {
      const short* ap0 = Vh + (size_t)(mw + l16) * 64 + quad * 8;
      const short* ap1 = ap0 + 16 * 64;
      const short* bp = W2bf + l16 * 64 + quad * 8;
      bf16x8 A00 = *(const bf16x8*)ap0, A01 = *(const bf16x8*)(ap0 + 32);
      bf16x8 A10 = *(const bf16x8*)ap1, A11 = *(const bf16x8*)(ap1 + 32);
      f32x4 acc[2][4] = {};
#pragma unroll
      for (int t = 0; t < 4; t++) {
        bf16x8 B0 = *(const bf16x8*)(bp + t * 16 * 64);
        bf16x8 B1 = *(const bf16x8*)(bp + t * 16 * 64 + 32);
        acc[0][t] = __builtin_amdgcn_mfma_f32_16x16x32_bf16(A00, B0, acc[0][t], 0, 0, 0);
        acc[0][t] = __builtin_amdgcn_mfma_f32_16x16x32_bf16(A01, B1, acc[0][t], 0, 0, 0);
        acc[1][t] = __builtin_amdgcn_mfma_f32_16x16x32_bf16(A10, B0, acc[1][t], 0, 0, 0);
        acc[1][t] = __builtin_amdgcn_mfma_f32_16x16x32_bf16(A11, B1, acc[1][t], 0, 0, 0);
      }
#pragma unroll
      for (int mt = 0; mt < 2; mt++)
#pragma unroll
        for (int r = 0; r < 4; r++) {
          int m = mw + mt * 16 + quad * 4 + r;
#pragma unroll
          for (int t = 0; t < 4; t++) {
            int n = t * 16 + l16;
            Vpp[(size_t)m * 64 + n] = acc[mt][t][r] + cvec[n];
          }
        }
    }
    return;
  }
  // ---- local windowed attention ----
  int wv = tid >> 6;
  int tile = (blockIdx.x - 256) * 4 + wv;   // 0..2047
  int bh = tile >> 7;
  int q0 = (tile & 127) * 16;
  int lane = tid & 63;
  int quad = lane >> 4, l16 = lane & 15;

  const short* qbase = Qh + (size_t)(bh * 2048 + q0 + l16) * 64 + quad * 8;
  bf16x8 a0 = *(const bf16x8*)qbase;
  bf16x8 a1 = *(const bf16x8*)(qbase + 32);

  int k0a = min(max(q0 - 2 + l16, 0), 2047);
  int k1a = min(q0 + 6 + l16, 2047);
  const short* kb0 = Kh + (size_t)(bh * 2048 + k0a) * 64 + quad * 8;
  const short* kb1 = Kh + (size_t)(bh * 2048 + k1a) * 64 + quad * 8;
  bf16x8 B00 = *(const bf16x8*)kb0;
  bf16x8 B01 = *(const bf16x8*)(kb0 + 32);
  bf16x8 B10 = *(const bf16x8*)kb1;
  bf16x8 B11 = *(const bf16x8*)(kb1 + 32);
  f32x4 C0 = {0.f, 0.f, 0.f, 0.f};
  f32x4 C1 = {0.f, 0.f, 0.f, 0.f};
  C0 = __builtin_amdgcn_mfma_f32_16x16x32_bf16(a0, B00, C0, 0, 0, 0);
  C0 = __builtin_amdgcn_mfma_f32_16x16x32_bf16(a1, B01, C0, 0, 0, 0);
  C1 = __builtin_amdgcn_mfma_f32_16x16x32_bf16(a0, B10, C1, 0, 0, 0);
  C1 = __builtin_amdgcn_mfma_f32_16x16x32_bf16(a1, B11, C1, 0, 0, 0);
#pragma unroll
  for (int r = 0; r < 4; r++) {
    Sloc[wv][0][quad * 4 + r][l16] = C0[r];
    Sloc[wv][1][quad * 4 + r][l16] = C1[r];
  }
  __builtin_amdgcn_wave_barrier();
  if (lane < 16) {
    int q = lane;
    float sc[5];
    bool ok[5];
#pragma unroll
    for (int j = 0; j < 5; j++) {
      int offq = q + j - 2;
      int sg = q0 + offq;
      ok[j] = (sg >= 0 && sg < SS);
      int t = offq <= 13 ? 0 : 1;
      int col = t ? offq - 6 : offq + 2;
      sc[j] = ok[j] ? Sloc[wv][t][q][col] : -3.0e38f;
    }
    float m = -3.0e38f;
#pragma unroll
    for (int j = 0; j < 5; j++) m = fmaxf(m, sc[j]);
    float e[5], l = 0.f;
#pragma unroll
    for (int j = 0; j < 5; j++) {
      e[j] = ok[j] ? __expf(sc[j] - m) : 0.f;
      l += e[j];
    }
    float inv = 1.f / l;
#pragma unroll
    for (int j = 0; j < 5; j++) wloc[wv][q][j] = e[j] * inv;
  }
  __builtin_amdgcn_wave_barrier();
  {
    int q = lane >> 2, jb = (lane & 3) * 16;
    int s = q0 + q;
    float acc[16] = {};
#pragma unroll
    for (int j = 0; j < 5; j++) {
      int sg = s + j - 2;
      if (sg >= 0 && sg < SS) {
        float w = wloc[wv][q][j];
        const short* vr = Vh + (size_t)(bh * 2048 + sg) * 64 + jb;
#pragma unroll
        for (int u = 0; u < 16; u += 4) {
          short4 v4 = *(const short4*)(vr + u);
          acc[u + 0] += w * bf2f(v4.x);
          acc[u + 1] += w * bf2f(v4.y);
          acc[u + 2] += w * bf2f(v4.z);
          acc[u + 3] += w * bf2f(v4.w);
        }
      }
    }
    float* orow = ctxl + (size_t)(bh * 2048 + s) * 64 + jb;
#pragma unroll
    for (int u = 0; u < 16; u += 4)
      *(float4*)(orow + u) =
          make_float4(acc[u], acc[u + 1], acc[u + 2], acc[u + 3]);
  }
}

// ---------------------------------------------------------------------------
// global sparse attention — v11: fragment-packed K, ZERO barriers, no LDS
// staging. The B-operand load is kf + g*1024 + f*512 + lane*8 — 64 lanes x
// 16B contiguous (1KB/wave/load). 128 independent iterations; compiler free
// to pipeline loads (no vmcnt(0) drain points). 4 waves/block stream the
// same frag sequence -> natural L1 sharing. Selection math identical to the
// r1/r8-verified forms.
// ---------------------------------------------------------------------------
__global__ __launch_bounds__(256, 4) void global_attn(
    const short* __restrict__ Qh, const short* __restrict__ Kfrag,
    const float* __restrict__ Vpp, const float* __restrict__ ctxl,
    short* __restrict__ ctxcb) {
  int tid = threadIdx.x;
  int wv = tid >> 6;
  int lane = tid & 63;
  int quad = lane >> 4, l16 = lane & 15;
  int p = blockIdx.x;                       // 0..511
  int bh = (p & 7) * 2 + ((p >> 3) & 1);    // XCD-affine
  int seg = p >> 4;                         // 0..31
  int tile = seg * 4 + wv;                  // tile within bh: 0..127
  int q0 = tile * 16;

  __shared__ float twl[4][16][17];
  __shared__ int   txl[4][16][17];

  const short* qbase = Qh + (size_t)(bh * 2048 + q0 + l16) * 64 + quad * 8;
  bf16x8 a0 = *(const bf16x8*)qbase;
  bf16x8 a1 = *(const bf16x8*)(qbase + 32);

  const short* kf = Kfrag + (size_t)bh * (128 * 1024) + lane * 8;

  unsigned er[4][8];
#pragma unroll
  for (int a = 0; a < 4; a++)
#pragma unroll
    for (int j = 0; j < 8; j++) er[a][j] = 0u;

  auto insert8 = [&](unsigned (&e)[8], unsigned cand) {
    unsigned n0, n1, n2, n3, n4, n5, n6, n7;
    asm("v_max_u32 %0, %1, %2" : "=v"(n0) : "v"(e[0]), "v"(cand));
    asm("v_med3_u32 %0, %1, %2, %3" : "=v"(n1) : "v"(e[0]), "v"(e[1]), "v"(cand));
    asm("v_med3_u32 %0, %1, %2, %3" : "=v"(n2) : "v"(e[1]), "v"(e[2]), "v"(cand));
    asm("v_med3_u32 %0, %1, %2, %3" : "=v"(n3) : "v"(e[2]), "v"(e[3]), "v"(cand));
    asm("v_med3_u32 %0, %1, %2, %3" : "=v"(n4) : "v"(e[3]), "v"(e[4]), "v"(cand));
    asm("v_med3_u32 %0, %1, %2, %3" : "=v"(n5) : "v"(e[4]), "v"(e[5]), "v"(cand));
    asm("v_med3_u32 %0, %1, %2, %3" : "=v"(n6) : "v"(e[5]), "v"(e[6]), "v"(cand));
    asm("v_med3_u32 %0, %1, %2, %3" : "=v"(n7) : "v"(e[6]), "v"(e[7]), "v"(cand));
    e[0] = n0; e[1] = n1; e[2] = n2; e[3] = n3;
    e[4] = n4; e[5] = n5; e[6] = n6; e[7] = n7;
  };
  auto mkcand = [&](float s, int idxr) -> unsigned {
    unsigned u = __float_as_uint(s);
    u ^= ((unsigned)((int)u >> 31)) | 0x80000000u;
    return (u & 0xFFFFF800u) | (unsigned)idxr;
  };

  int idxb = 2047 - l16;
#pragma unroll 4
  for (int g = 0; g < 128; g++) {
    bf16x8 B00 = *(const bf16x8*)(kf + g * 1024);
    bf16x8 B01 = *(const bf16x8*)(kf + g * 1024 + 512);
    f32x4 C0 = {0.f, 0.f, 0.f, 0.f};
    C0 = __builtin_amdgcn_mfma_f32_16x16x32_bf16(a0, B00, C0, 0, 0, 0);
    C0 = __builtin_amdgcn_mfma_f32_16x16x32_bf16(a1, B01, C0, 0, 0, 0);
    int idxr = idxb - (g << 4);
    insert8(er[0], mkcand(C0[0], idxr));
    insert8(er[1], mkcand(C0[1], idxr));
    insert8(er[2], mkcand(C0[2], idxr));
    insert8(er[3], mkcand(C0[3], idxr));
  }

  // Extraction + inline softmax (verified form).
  {
    float mval[4] = {0.f, 0.f, 0.f, 0.f};
    float lsum[4] = {0.f, 0.f, 0.f, 0.f};
    float myev[4] = {0.f, 0.f, 0.f, 0.f};
    int myki[4] = {0, 0, 0, 0};
#pragma unroll
    for (int t = 0; t < 16; t++) {
#pragma unroll
      for (int a = 0; a < 4; a++) {
        unsigned w = er[a][0];
#pragma unroll
        for (int mm = 1; mm <= 8; mm <<= 1) {
          unsigned o = (unsigned)__shfl_xor((int)w, mm);
          w = w > o ? w : o;
        }
        bool pop = (er[a][0] == w);
#pragma unroll
        for (int j = 0; j < 7; j++) er[a][j] = pop ? er[a][j + 1] : er[a][j];
        er[a][7] = pop ? 0u : er[a][7];
        unsigned wb = w & 0xFFFFF800u;
        unsigned uu = (w & 0x80000000u) ? (wb ^ 0x80000000u) : ~wb;
        float sv = (w == 0u) ? -1.0e30f : __uint_as_float(uu);
        if (t == 0) mval[a] = sv;
        float ex = __expf(sv - mval[a]);
        lsum[a] += ex;
        if (l16 == t) { myev[a] = ex; myki[a] = 2047 - (int)(w & 0x7FFu); }
      }
    }
#pragma unroll
    for (int a = 0; a < 4; a++) {
      twl[wv][quad * 4 + a][l16] = myev[a] / lsum[a];
      txl[wv][quad * 4 + a][l16] = myki[a];
    }
  }
  __builtin_amdgcn_wave_barrier();

  // Per-wave weighted gather of prefolded Vpp rows; combine with local ctx.
  {
    int q = lane >> 2, d0 = (lane & 3) * 16;
    int b = bh >> 3, hh = bh & 7;
    const float* vball = Vpp + (size_t)bh * (2048 * 64) + d0;
    float acc[16];
#pragma unroll
    for (int u = 0; u < 16; u++) acc[u] = 0.f;
#pragma unroll 4
    for (int j = 0; j < 16; j++) {
      float w = twl[wv][q][j];
      const float* vr = vball + (size_t)txl[wv][q][j] * 64;
#pragma unroll
      for (int u = 0; u < 16; u += 4) {
        float4 v = *(const float4*)(vr + u);
        acc[u + 0] += w * v.x;
        acc[u + 1] += w * v.y;
        acc[u + 2] += w * v.z;
        acc[u + 3] += w * v.w;
      }
    }
    int s = q0 + q;
    const float* lrow = ctxl + (size_t)(bh * 2048 + s) * 64 + d0;
    short* orow = ctxcb + (size_t)(b * 2048 + s) * 512 + hh * 64 + d0;
#pragma unroll
    for (int u = 0; u < 16; u += 4) {
      float4 lv = *(const float4*)(lrow + u);
      short4 o;
      o.x = f2bf(0.5f * (lv.x + acc[u + 0]));
      o.y = f2bf(0.5f * (lv.y + acc[u + 1]));
      o.z = f2bf(0.5f * (lv.z + acc[u + 2]));
      o.w = f2bf(0.5f * (lv.w + acc[u + 3]));
      *(short4*)(orow + u) = o;
    }
  }
}

// ---------------------------------------------------------------------------
// MFMA Wo gemm: 128-row blocks, wave = 32 rows. Residual from bf16 hbf.
// ---------------------------------------------------------------------------
__global__ __launch_bounds__(256, 4) void gemm_wo(
    const short* __restrict__ Abf, const short* __restrict__ Wbf,
    const float* __restrict__ bo, const short* __restrict__ hbf,
    float* __restrict__ outp) {
  int m0 = blockIdx.x * 128;
  int n0 = blockIdx.y * 64;
  int tid = threadIdx.x;
  int wvv = tid >> 6, lane = tid & 63;
  int quad = lane >> 4, l16 = lane & 15;
  int mw = m0 + wvv * 32;
  const short* ap0 = Abf + (size_t)(mw + l16) * 512 + quad * 8;
  const short* ap1 = ap0 + 16 * 512;
  const short* bp = Wbf + (size_t)(n0 + l16) * 512 + quad * 8;
  f32x4 acc[2][4] = {};
  bf16x8 cA0 = *(const bf16x8*)ap0;
  bf16x8 cA1 = *(const bf16x8*)ap1;
  bf16x8 cB0 = *(const bf16x8*)(bp + 0 * 16 * 512);
  bf16x8 cB1 = *(const bf16x8*)(bp + 1 * 16 * 512);
  bf16x8 cB2 = *(const bf16x8*)(bp + 2 * 16 * 512);
  bf16x8 cB3 = *(const bf16x8*)(bp + 3 * 16 * 512);
#pragma unroll 2
  for (int ks = 0; ks < 16; ks++) {
    int offn = (ks + 1 < 16 ? ks + 1 : 15) * 32;
    bf16x8 nA0 = *(const bf16x8*)(ap0 + offn);
    bf16x8 nA1 = *(const bf16x8*)(ap1 + offn);
    bf16x8 nB0 = *(const bf16x8*)(bp + 0 * 16 * 512 + offn);
    bf16x8 nB1 = *(const bf16x8*)(bp + 1 * 16 * 512 + offn);
    bf16x8 nB2 = *(const bf16x8*)(bp + 2 * 16 * 512 + offn);
    bf16x8 nB3 = *(const bf16x8*)(bp + 3 * 16 * 512 + offn);
    acc[0][0] = __builtin_amdgcn_mfma_f32_16x16x32_bf16(cA0, cB0, acc[0][0], 0, 0, 0);
    acc[1][0] = __builtin_amdgcn_mfma_f32_16x16x32_bf16(cA1, cB0, acc[1][0], 0, 0, 0);
    acc[0][1] = __builtin_amdgcn_mfma_f32_16x16x32_bf16(cA0, cB1, acc[0][1], 0, 0, 0);
    acc[1][1] = __builtin_amdgcn_mfma_f32_16x16x32_bf16(cA1, cB1, acc[1][1], 0, 0, 0);
    acc[0][2] = __builtin_amdgcn_mfma_f32_16x16x32_bf16(cA0, cB2, acc[0][2], 0, 0, 0);
    acc[1][2] = __builtin_amdgcn_mfma_f32_16x16x32_bf16(cA1, cB2, acc[1][2], 0, 0, 0);
    acc[0][3] = __builtin_amdgcn_mfma_f32_16x16x32_bf16(cA0, cB3, acc[0][3], 0, 0, 0);
    acc[1][3] = __builtin_amdgcn_mfma_f32_16x16x32_bf16(cA1, cB3, acc[1][3], 0, 0, 0);
    cA0 = nA0; cA1 = nA1;
    cB0 = nB0; cB1 = nB1; cB2 = nB2; cB3 = nB3;
  }
#pragma unroll
  for (int mt = 0; mt < 2; mt++) {
#pragma unroll
    for (int r = 0; r < 4; r++) {
      int m = mw + mt * 16 + quad * 4 + r;
#pragma unroll
      for (int t = 0; t < 4; t++) {
        int n = n0 + t * 16 + l16;
        outp[(size_t)m * 512 + n] =
            acc[mt][t][r] + bo[n] + bf2f(hbf[(size_t)m * 512 + n]);
      }
    }
  }
}

// ---------------------------------------------------------------------------
// layernorm in place on d_out, one block per row
// ---------------------------------------------------------------------------
__global__ __launch_bounds__(256) void ln_kernel(float* __restrict__ o,
                                                 const float* __restrict__ g,
                                                 const float* __restrict__ bb) {
  int row = blockIdx.x;
  int tid = threadIdx.x;
  float v0 = o[row * 512 + tid];
  float v1 = o[row * 512 + 256 + tid];
  float s = v0 + v1;
  float s2 = v0 * v0 + v1 * v1;
#pragma unroll
  for (int off = 1; off < 64; off <<= 1) {
    s += __shfl_xor(s, off);
    s2 += __shfl_xor(s2, off);
  }
  __shared__ float ps[4], ps2[4];
  int w = tid >> 6;
  if ((tid & 63) == 0) { ps[w] = s; ps2[w] = s2; }
  __syncthreads();
  float S = ps[0] + ps[1] + ps[2] + ps[3];
  float S2 = ps2[0] + ps2[1] + ps2[2] + ps2[3];
  float mu = S * (1.f / 512.f);
  float var = S2 * (1.f / 512.f) - mu * mu;
  float inv = rsqrtf(var + 1e-5f);
  o[row * 512 + tid] = (v0 - mu) * inv * g[tid] + bb[tid];
  o[row * 512 + 256 + tid] = (v1 - mu) * inv * g[tid + 256] + bb[tid + 256];
}

// ---------------------------------------------------------------------------
extern "C" void kernel_launch(void* const* d_in, const int* in_sizes, int n_in,
                              void* d_out, int out_size, void* d_ws,
                              size_t ws_size, hipStream_t stream) {
  const float* x   = (const float*)d_in[0];
  const float* w1  = (const float*)d_in[1];
  const float* b1  = (const float*)d_in[2];
  const float* w2  = (const float*)d_in[3];
  const float* b2  = (const float*)d_in[4];
  const float* w3  = (const float*)d_in[5];
  const float* b3  = (const float*)d_in[6];
  const float* Wq  = (const float*)d_in[7];
  const float* bq  = (const float*)d_in[8];
  const float* Wk  = (const float*)d_in[9];
  const float* bk  = (const float*)d_in[10];
  const float* Wv  = (const float*)d_in[11];
  const float* bv  = (const float*)d_in[12];
  const float* Wkp = (const float*)d_in[13];
  const float* bkp = (const float*)d_in[14];
  const float* Wvp = (const float*)d_in[15];
  const float* bvp = (const float*)d_in[16];
  const float* Wo  = (const float*)d_in[17];
  const float* bo  = (const float*)d_in[18];
  const float* lng = (const float*)d_in[19];
  const float* lnb = (const float*)d_in[20];

  float* p = (float*)d_ws;
  short* Wallbf = (short*)p;  p += 786432;
  float* ball   = p;          p += 2048;
  short* Wobf   = (short*)p;  p += 262144;
  short* Wkpbf  = (short*)p;  p += 4096;
  short* W2bf   = (short*)p;  p += 4096;
  float* cvec   = p;          p += 64;
  short* xbfp   = (short*)p;  p += 262912;
  short* Wcbf   = (short*)p;  p += 229376;
  float* bcat   = p;          p += 512;
  short* hbf    = (short*)p;  p += 1048576;
  short* Qh     = (short*)p;  p += 1048576;
  short* Kh     = (short*)p;  p += 1048576;
  short* Vh     = (short*)p;  p += 1048576;
  short* Kfrag  = (short*)p;  p += 1048576;
  float* Vpp    = p;          p += 2097152;
  float* ctxl   = p;          p += 2097152;
  short* ctxcb  = (short*)p;  p += 1048576;
  float* outF   = (float*)d_out;

  prep_kernel<<<512, 256, 0, stream>>>(x, w1, b1, w2, b2, w3, b3, Wq, Wk, Wv,
                                       bq, bk, bv, Wo, Wkp, Wvp, bvp, Wallbf,
                                       ball, Wobf, Wkpbf, W2bf, cvec, xbfp,
                                       Wcbf, bcat);
  {
    dim3 g(32, 8);
    gemm_conv<<<g, 256, 0, stream>>>(xbfp, Wcbf, bcat, hbf);
  }
  {
    dim3 g(32, 24);
    gemm_qkv<<<g, 256, 0, stream>>>(hbf, Wallbf, ball, Qh, Kh, Vh);
  }
  kpvp_local_kernel<<<768, 256, 0, stream>>>(Kh, Vh, Wkpbf, bkp, W2bf, cvec,
                                             Kfrag, Vpp, Qh, ctxl);
  global_attn<<<512, 256, 0, stream>>>(Qh, Kfrag, Vpp, ctxl, ctxcb);
  {
    dim3 g(32, 8);
    gemm_wo<<<g, 256, 0, stream>>>(ctxcb, Wobf, bo, hbf, outF);
  }
  ln_kernel<<<4096, 256, 0, stream>>>(outF, lng, lnb);
}